// Round 7
// baseline (1814.378 us; speedup 1.0000x reference)
//
#include <hip/hip_runtime.h>
#include <hip/hip_cooperative_groups.h>
#include <math.h>

#define NN 4096
#define DD 256
#define TT 32
#define GAMMA (1.0f/256.0f)
#define ITERS 10
#define JBP 8            // j-chunks in matvec
#define JCH 512          // j per matvec block
#define IB  128          // i-rows per matvec block
#define BROW (JCH + 8)   // padded LDS row: 1040 B -> benign banks
#define KB_PAD 40        // f16 elems per LDS row in k_build staging

typedef __attribute__((ext_vector_type(8))) _Float16 f16x8;
typedef __attribute__((ext_vector_type(4))) float f32x4;

struct CGParams {
    const float* X; const float* y;
    _Float16* Xh; float* x2;
    _Float16* Kh;
    float* r; float* p; float* s_; float* x;
    _Float16* vh; _Float16* vl;
    float* part; float* rrp; float* rKvp; float* scal;
    float* out;
};

// ---------------------------------------------------------------- matvec phase
// part[jb][t][i] = sum_{j in jb} K[i][j]*v[t][j]; v = vh + vl (f16 hi/lo).
// red: also rKvp[t][bid] = sum_{i in blk} r[t][i]*(Kv)[t][i]
__device__ __forceinline__ void matvec_phase(const CGParams& P, unsigned char* SM,
                                             int bid, int tid, int wid, int lane,
                                             int l15, int l4, bool red) {
    _Float16* Bh = (_Float16*)SM;               // 32*520 f16 = 33280 B
    _Float16* Bl = Bh + 32 * BROW;              // 33280 B
    float* redb = (float*)(Bl + 32 * BROW);     // 8*33 floats
    const int ib = bid & 31, jb = bid >> 5;
    #pragma unroll
    for (int s = 0; s < 4; ++s) {
        int c = s * 512 + tid;                  // 2048 chunks of 8 f16
        int row = c >> 6, col8 = c & 63;
        *(uint4*)(Bh + row * BROW + col8 * 8) = *(const uint4*)(P.vh + (size_t)row * NN + jb * JCH + col8 * 8);
        *(uint4*)(Bl + row * BROW + col8 * 8) = *(const uint4*)(P.vl + (size_t)row * NN + jb * JCH + col8 * 8);
    }
    __syncthreads();
    const _Float16* Ap  = P.Kh + (size_t)(ib * IB + wid * 16 + l15) * NN + jb * JCH + l4 * 8;
    const _Float16* bhp = Bh + l15 * BROW + l4 * 8;
    const _Float16* blp = Bl + l15 * BROW + l4 * 8;
    f32x4 acc0 = {}, acc1 = {};
    #pragma unroll 4
    for (int jc = 0; jc < JCH; jc += 32) {
        f16x8 a   = *(const f16x8*)(Ap + jc);
        f16x8 bh0 = *(const f16x8*)(bhp + jc);
        f16x8 bh1 = *(const f16x8*)(bhp + 16 * BROW + jc);
        f16x8 bl0 = *(const f16x8*)(blp + jc);
        f16x8 bl1 = *(const f16x8*)(blp + 16 * BROW + jc);
        acc0 = __builtin_amdgcn_mfma_f32_16x16x32_f16(a, bh0, acc0, 0, 0, 0);
        acc1 = __builtin_amdgcn_mfma_f32_16x16x32_f16(a, bh1, acc1, 0, 0, 0);
        acc0 = __builtin_amdgcn_mfma_f32_16x16x32_f16(a, bl0, acc0, 0, 0, 0);
        acc1 = __builtin_amdgcn_mfma_f32_16x16x32_f16(a, bl1, acc1, 0, 0, 0);
    }
    __syncthreads();                            // done reading Bh/Bl -> reuse as tl
    float* tl = (float*)Bh;                     // [8][32][17] floats
    #pragma unroll
    for (int rg = 0; rg < 4; ++rg) {
        tl[(wid * 32 + l15) * 17 + l4 * 4 + rg]      = acc0[rg];
        tl[(wid * 32 + 16 + l15) * 17 + l4 * 4 + rg] = acc1[rg];
    }
    __syncthreads();
    #pragma unroll
    for (int q = 0; q < 8; ++q) {
        int idx = q * 64 + lane;
        int t = idx >> 4, il = idx & 15;
        int gi = ib * IB + wid * 16 + il;
        float val = tl[(wid * 32 + t) * 17 + il];
        P.part[((size_t)jb * TT + t) * NN + gi] = val;
        if (red) {
            float cq = P.r[(size_t)t * NN + gi] * val;
            #pragma unroll
            for (int o = 8; o; o >>= 1) cq += __shfl_down(cq, o);
            if (il == 0) redb[wid * 33 + t] = cq;
        }
    }
    if (red) {
        __syncthreads();
        if (tid < 32) {
            float s = 0.f;
            #pragma unroll
            for (int u = 0; u < 8; ++u) s += redb[u * 33 + tid];
            P.rKvp[tid * 256 + bid] = s;
        }
    }
}

// ---------------------------------------------------------------- Chronopoulos-Gear update
__device__ __forceinline__ void cupd_phase(const CGParams& P, int bid, int tid,
                                           int wid, int lane, int j, bool last,
                                           float* red8, float* sc2) {
    const int t = bid >> 3, c = bid & 7;
    const float* rrp_in  = P.rrp + (j & 1) * 256;
    float*       rrp_out = P.rrp + ((j + 1) & 1) * 256;
    const float* scal_in = P.scal + (j & 1) * 64;
    float*       scal_out= P.scal + ((j + 1) & 1) * 64;
    if (wid == 0) {                              // one wave computes scalars
        float rw_ = 0.f;
        #pragma unroll
        for (int u = lane; u < 256; u += 64) rw_ += P.rKvp[t * 256 + u];
        float rr_ = (lane < 8) ? rrp_in[t * 8 + lane] : 0.f;
        #pragma unroll
        for (int o = 32; o; o >>= 1) { rw_ += __shfl_down(rw_, o); rr_ += __shfl_down(rr_, o); }
        if (lane == 0) {
            float rr = rr_;
            float rw = rw_ + rr;                 // r.w = r.Kv + r.r  (A = K+I)
            float alpha, beta;
            if (j == 0) { beta = 0.f; alpha = rr / rw; }
            else {
                float ap = scal_in[t], rrprev = scal_in[TT + t];
                beta = rr / rrprev;
                alpha = rr / (rw - (beta / ap) * rr);
            }
            sc2[0] = alpha; sc2[1] = beta;
            if (c == 0) { scal_out[t] = alpha; scal_out[TT + t] = rr; }
        }
    }
    __syncthreads();
    const float alpha = sc2[0], beta = sc2[1];
    int i = c * 512 + tid;
    size_t off = (size_t)t * NN + i;
    float s = 0.f;
    #pragma unroll
    for (int b = 0; b < JBP; ++b) s += P.part[((size_t)b * TT + t) * NN + i];
    float rv = P.r[off];
    float wv = s + rv;                           // w = Kv + r
    float pn = (j == 0) ? rv : fmaf(beta, P.p[off], rv);
    float sn = (j == 0) ? wv : fmaf(beta, P.s_[off], wv);
    P.p[off] = pn; P.s_[off] = sn;
    float xn = P.x[off] + alpha * pn;
    P.x[off] = xn;
    float rn = rv - alpha * sn;
    P.r[off] = rn;
    float vout = last ? xn : rn;                 // last iter: emit x for predict
    _Float16 h = (_Float16)vout;
    P.vh[off] = h; P.vl[off] = (_Float16)(vout - (float)h);
    float v = rn * rn;
    #pragma unroll
    for (int o = 32; o; o >>= 1) v += __shfl_down(v, o);
    if (lane == 0) red8[wid] = v;
    __syncthreads();
    if (tid == 0) {
        float tot = 0.f;
        #pragma unroll
        for (int u = 0; u < 8; ++u) tot += red8[u];
        rrp_out[t * 8 + c] = tot;
    }
}

// ---------------------------------------------------------------- the whole solve, one kernel
__global__ __launch_bounds__(512) void cg_mega(CGParams P) {
    namespace cg = cooperative_groups;
    cg::grid_group grid = cg::this_grid();
    __shared__ __align__(16) unsigned char SM[67648];
    __shared__ float red8[8];
    __shared__ float sc2[2];
    const int bid = blockIdx.x;
    const int tid = threadIdx.x;
    const int wid = tid >> 6, lane = tid & 63;
    const int l15 = lane & 15, l4 = lane >> 4;

    // ---- phase X2: f16-convert X + row norms (16 rows/block)
    {
        int row = bid * 16 + wid * 2 + (lane >> 5);
        int l32 = lane & 31;
        const float* xr = P.X + (size_t)row * DD + l32 * 8;
        float4 a = *(const float4*)xr;
        float4 b = *(const float4*)(xr + 4);
        f16x8 hv;
        hv[0] = (_Float16)a.x; hv[1] = (_Float16)a.y; hv[2] = (_Float16)a.z; hv[3] = (_Float16)a.w;
        hv[4] = (_Float16)b.x; hv[5] = (_Float16)b.y; hv[6] = (_Float16)b.z; hv[7] = (_Float16)b.w;
        *(f16x8*)(P.Xh + (size_t)row * DD + l32 * 8) = hv;
        float s = a.x*a.x + a.y*a.y + a.z*a.z + a.w*a.w + b.x*b.x + b.y*b.y + b.z*b.z + b.w*b.w;
        #pragma unroll
        for (int o = 16; o; o >>= 1) s += __shfl_xor(s, o);
        if (l32 == 0) P.x2[row] = s;
    }
    // ---- phase INIT: r = y^T, x = 0, v = f16 hi/lo of r, rr partials
    {
        int t = bid >> 3, c = bid & 7;
        int i = c * 512 + tid;
        float v = P.y[(size_t)i * TT + t];
        size_t off = (size_t)t * NN + i;
        P.r[off] = v; P.x[off] = 0.f;
        _Float16 h = (_Float16)v;
        P.vh[off] = h; P.vl[off] = (_Float16)(v - (float)h);
        float s = v * v;
        #pragma unroll
        for (int o = 32; o; o >>= 1) s += __shfl_down(s, o);
        if (lane == 0) red8[wid] = s;
        __syncthreads();
        if (tid == 0) {
            float tot = 0.f;
            #pragma unroll
            for (int u = 0; u < 8; ++u) tot += red8[u];
            P.rrp[t * 8 + c] = tot;
        }
    }
    __threadfence();
    grid.sync();

    // ---- phase KB: K = exp(-g*d2) f16; two 128x256 tiles per block
    {
        _Float16* As = (_Float16*)SM;            // 128*40
        _Float16* Bs = As + 128 * KB_PAD;        // 256*40
        const int wr = wid >> 1, wc = wid & 1;
        for (int tt = 0; tt < 2; ++tt) {
            int idx = bid * 2 + tt;              // 512 tiles: 32 (i) x 16 (j)
            int i0 = (idx & 31) * 128;
            int j0 = (idx >> 5) * 256;
            f32x4 acc[2][8] = {};
            for (int kc = 0; kc < DD; kc += 32) {
                __syncthreads();
                { int rowa = tid >> 2, ch = tid & 3;
                  *(uint4*)(As + rowa * KB_PAD + ch * 8) =
                      *(const uint4*)(P.Xh + (size_t)(i0 + rowa) * DD + kc + ch * 8); }
                #pragma unroll
                for (int s2 = 0; s2 < 2; ++s2) {
                    int q = s2 * 512 + tid;
                    int rowb = q >> 2, ch = q & 3;
                    *(uint4*)(Bs + rowb * KB_PAD + ch * 8) =
                        *(const uint4*)(P.Xh + (size_t)(j0 + rowb) * DD + kc + ch * 8);
                }
                __syncthreads();
                f16x8 af[2], bf[8];
                #pragma unroll
                for (int m = 0; m < 2; ++m)
                    af[m] = *(const f16x8*)(As + (wr * 32 + m * 16 + l15) * KB_PAD + l4 * 8);
                #pragma unroll
                for (int n = 0; n < 8; ++n)
                    bf[n] = *(const f16x8*)(Bs + (wc * 128 + n * 16 + l15) * KB_PAD + l4 * 8);
                #pragma unroll
                for (int m = 0; m < 2; ++m)
                    #pragma unroll
                    for (int n = 0; n < 8; ++n)
                        acc[m][n] = __builtin_amdgcn_mfma_f32_16x16x32_f16(af[m], bf[n], acc[m][n], 0, 0, 0);
            }
            #pragma unroll
            for (int m = 0; m < 2; ++m) {
                #pragma unroll
                for (int rg = 0; rg < 4; ++rg) {
                    int i = i0 + wr * 32 + m * 16 + l4 * 4 + rg;
                    float x2i = P.x2[i];
                    #pragma unroll
                    for (int n = 0; n < 8; ++n) {
                        int jj = j0 + wc * 128 + n * 16 + l15;
                        float d2 = fmaxf(x2i + P.x2[jj] - 2.f * acc[m][n][rg], 0.f);
                        P.Kh[(size_t)i * NN + jj] = (_Float16)__expf(-GAMMA * d2);
                    }
                }
            }
        }
    }
    __threadfence();
    grid.sync();

    // ---- CG loop
    for (int j = 0; j < ITERS; ++j) {
        matvec_phase(P, SM, bid, tid, wid, lane, l15, l4, true);
        __threadfence();
        grid.sync();
        cupd_phase(P, bid, tid, wid, lane, j, j == ITERS - 1, red8, sc2);
        __threadfence();
        grid.sync();
    }

    // ---- predict: part = K @ x
    matvec_phase(P, SM, bid, tid, wid, lane, l15, l4, false);
    __threadfence();
    grid.sync();

    // ---- output: out[i][t] = sum_b part, transposed via LDS (16 rows/block)
    {
        float* st = (float*)SM;                  // [32][17]
        int i0 = bid * 16;
        int t = tid >> 4, il = tid & 15;
        float s = 0.f;
        #pragma unroll
        for (int b = 0; b < JBP; ++b) s += P.part[((size_t)b * TT + t) * NN + i0 + il];
        __syncthreads();
        st[t * 17 + il] = s;
        __syncthreads();
        int t2 = tid & 31, il2 = tid >> 5;
        P.out[(size_t)(i0 + il2) * TT + t2] = st[t2 * 17 + il2];
    }
}

extern "C" void kernel_launch(void* const* d_in, const int* in_sizes, int n_in,
                              void* d_out, int out_size, void* d_ws, size_t ws_size,
                              hipStream_t stream) {
    CGParams P;
    P.X   = (const float*)d_in[0];   // [N, D]
    P.y   = (const float*)d_in[1];   // [N, T]
    P.out = (float*)d_out;           // [N, T]
    unsigned char* w = (unsigned char*)d_ws;
    P.Kh   = (_Float16*)w;  w += (size_t)NN * NN * 2;        // 32 MB
    P.part = (float*)w;     w += (size_t)JBP * TT * NN * 4;  // 4 MB
    P.r    = (float*)w;     w += (size_t)TT * NN * 4;
    P.p    = (float*)w;     w += (size_t)TT * NN * 4;
    P.s_   = (float*)w;     w += (size_t)TT * NN * 4;
    P.x    = (float*)w;     w += (size_t)TT * NN * 4;
    P.vh   = (_Float16*)w;  w += (size_t)TT * NN * 2;
    P.vl   = (_Float16*)w;  w += (size_t)TT * NN * 2;
    P.Xh   = (_Float16*)w;  w += (size_t)NN * DD * 2;        // 2 MB
    P.x2   = (float*)w;     w += (size_t)NN * 4;
    P.rrp  = (float*)w;     w += 512 * 4;
    P.rKvp = (float*)w;     w += 32 * 256 * 4;
    P.scal = (float*)w;     w += 128 * 4;
    void* kargs[] = { (void*)&P };
    hipLaunchCooperativeKernel((void*)cg_mega, dim3(256), dim3(512), kargs, 0, stream);
}

// Round 9
// 320.275 us; speedup vs baseline: 5.6651x; 5.6651x over previous
//
#include <hip/hip_runtime.h>
#include <math.h>

#define NN 4096
#define DD 256
#define TT 32
#define GAMMA (1.0f/256.0f)
#define ITERS 10
#define JBP 16           // j-chunks in matvec
#define JCH 256          // j per matvec block
#define IB  128          // i-rows per matvec block
#define BROW (JCH + 8)   // padded LDS row (f16 elems): 528 B stride
#define KB_PAD 40        // f16 elems per LDS row in k_build staging

typedef __attribute__((ext_vector_type(8))) _Float16 f16x8;
typedef __attribute__((ext_vector_type(4))) _Float16 f16x4;
typedef __attribute__((ext_vector_type(4))) float f32x4;

// ---------------------------------------------------------------- x2 + f16 convert of X
__global__ __launch_bounds__(256) void x2conv(const float* __restrict__ X,
                                              float* __restrict__ x2,
                                              _Float16* __restrict__ Xh) {
    int wid = threadIdx.x >> 6, lane = threadIdx.x & 63;
    int row = blockIdx.x * 4 + wid;
    const float* xr = X + (size_t)row * DD;
    float4 v = *(const float4*)(xr + lane * 4);
    float s = v.x * v.x + v.y * v.y + v.z * v.z + v.w * v.w;
    #pragma unroll
    for (int o = 32; o; o >>= 1) s += __shfl_down(s, o);
    if (lane == 0) x2[row] = s;
    f16x4 h;
    h[0] = (_Float16)v.x; h[1] = (_Float16)v.y; h[2] = (_Float16)v.z; h[3] = (_Float16)v.w;
    *(f16x4*)(Xh + (size_t)row * DD + lane * 4) = h;
}

// ---------------------------------------------------------------- K = exp(-g*d2), f16 out
// 128(i) x 256(j) tile, LDS-staged, 4 waves each 64x128 (4x8 MFMA frags).
__global__ __launch_bounds__(256) void k_build(const _Float16* __restrict__ Xh,
                                               const float* __restrict__ x2,
                                               _Float16* __restrict__ Kh) {
    __shared__ _Float16 As[128 * KB_PAD];   // 10240 B
    __shared__ _Float16 Bs[256 * KB_PAD];   // 20480 B
    const int i0 = blockIdx.x * 128, j0 = blockIdx.y * 256;
    const int tid = threadIdx.x;
    const int wid = tid >> 6, lane = tid & 63;
    const int wr = wid >> 1, wc = wid & 1;
    const int l15 = lane & 15, l4 = lane >> 4;
    f32x4 acc[4][8] = {};
    for (int kc = 0; kc < DD; kc += 32) {
        __syncthreads();
        #pragma unroll
        for (int s = 0; s < 2; ++s) {             // A: 128 rows x 4 chunks of 8
            int idx = s * 256 + tid;
            int row = idx >> 2, c = idx & 3;
            *(uint4*)(As + row * KB_PAD + c * 8) =
                *(const uint4*)(Xh + (size_t)(i0 + row) * DD + kc + c * 8);
        }
        #pragma unroll
        for (int s = 0; s < 4; ++s) {             // B: 256 rows x 4 chunks of 8
            int idx = s * 256 + tid;
            int row = idx >> 2, c = idx & 3;
            *(uint4*)(Bs + row * KB_PAD + c * 8) =
                *(const uint4*)(Xh + (size_t)(j0 + row) * DD + kc + c * 8);
        }
        __syncthreads();
        f16x8 af[4], bfr[8];
        #pragma unroll
        for (int m = 0; m < 4; ++m)
            af[m] = *(const f16x8*)(As + (wr * 64 + m * 16 + l15) * KB_PAD + l4 * 8);
        #pragma unroll
        for (int n = 0; n < 8; ++n)
            bfr[n] = *(const f16x8*)(Bs + (wc * 128 + n * 16 + l15) * KB_PAD + l4 * 8);
        #pragma unroll
        for (int m = 0; m < 4; ++m)
            #pragma unroll
            for (int n = 0; n < 8; ++n)
                acc[m][n] = __builtin_amdgcn_mfma_f32_16x16x32_f16(af[m], bfr[n], acc[m][n], 0, 0, 0);
    }
    #pragma unroll
    for (int m = 0; m < 4; ++m) {
        #pragma unroll
        for (int rg = 0; rg < 4; ++rg) {
            int i = i0 + wr * 64 + m * 16 + l4 * 4 + rg;
            float x2i = x2[i];
            #pragma unroll
            for (int n = 0; n < 8; ++n) {
                int j = j0 + wc * 128 + n * 16 + l15;
                float d2 = fmaxf(x2i + x2[j] - 2.f * acc[m][n][rg], 0.f);
                Kh[(size_t)i * NN + j] = (_Float16)__expf(-GAMMA * d2);
            }
        }
    }
}

// ---------------------------------------------------------------- CG init: r = y^T (fp32 + f16 hi/lo), x = 0
__global__ __launch_bounds__(512) void cg_init(const float* __restrict__ y,
                                               float* __restrict__ r, float* __restrict__ x,
                                               _Float16* __restrict__ vh,
                                               _Float16* __restrict__ vl,
                                               float* __restrict__ rrp) {
    int t = blockIdx.x, c = blockIdx.y, tid = threadIdx.x;
    int i = c * 512 + tid;
    float v = y[(size_t)i * TT + t];
    size_t off = (size_t)t * NN + i;
    r[off] = v; x[off] = 0.f;
    _Float16 h = (_Float16)v;
    vh[off] = h; vl[off] = (_Float16)(v - (float)h);
    float s = v * v;
    #pragma unroll
    for (int o = 32; o; o >>= 1) s += __shfl_down(s, o);
    __shared__ float red[8];
    if ((tid & 63) == 0) red[tid >> 6] = s;
    __syncthreads();
    if (tid == 0) {
        float tot = 0.f;
        #pragma unroll
        for (int u = 0; u < 8; ++u) tot += red[u];
        rrp[t * 8 + c] = tot;
    }
}

// ---------------------------------------------------------------- matvec: part[jb][t][i] = sum_{j in jb} K[i][j]*v[t][j]
// Block = 128 i-rows (8 waves x 16) x 256 j. v (hi/lo) staged in LDS (34 KB -> 2 blocks/CU).
// RED=1: also emit rKvp[t][bid] = sum_{i in blk} r[t][i] * (Kv)[t][i]
template<int RED>
__global__ __launch_bounds__(512) void matvec_part(const _Float16* __restrict__ Kh,
                                                   const _Float16* __restrict__ vh,
                                                   const _Float16* __restrict__ vl,
                                                   const float* __restrict__ r,
                                                   float* __restrict__ part,
                                                   float* __restrict__ rKvp) {
    __shared__ __align__(16) _Float16 Bbuf[2 * 32 * BROW];   // 33792 B (hi | lo)
    __shared__ float redb[8][33];
    _Float16* Bh = Bbuf;
    _Float16* Bl = Bbuf + 32 * BROW;
    const int ib = blockIdx.x;                    // 32
    const int jb = blockIdx.y;                    // 16
    const int bid = jb * 32 + ib;                 // 0..511
    const int tid = threadIdx.x;
    const int wid = tid >> 6, lane = tid & 63;
    const int l15 = lane & 15, l4 = lane >> 4;
    // stage v: 32 t-rows x 256 j, hi and lo
    #pragma unroll
    for (int s = 0; s < 2; ++s) {
        int c = s * 512 + tid;                    // 1024 chunks of 8 f16
        int row = c >> 5, col8 = c & 31;
        *(uint4*)(Bh + row * BROW + col8 * 8) =
            *(const uint4*)(vh + (size_t)row * NN + jb * JCH + col8 * 8);
        *(uint4*)(Bl + row * BROW + col8 * 8) =
            *(const uint4*)(vl + (size_t)row * NN + jb * JCH + col8 * 8);
    }
    __syncthreads();
    const _Float16* Ap  = Kh + (size_t)(ib * IB + wid * 16 + l15) * NN + jb * JCH + l4 * 8;
    const _Float16* bhp = Bh + l15 * BROW + l4 * 8;
    const _Float16* blp = Bl + l15 * BROW + l4 * 8;
    f32x4 acc0 = {}, acc1 = {};
    #pragma unroll 4
    for (int jc = 0; jc < JCH; jc += 32) {
        f16x8 a   = *(const f16x8*)(Ap + jc);
        f16x8 bh0 = *(const f16x8*)(bhp + jc);
        f16x8 bh1 = *(const f16x8*)(bhp + 16 * BROW + jc);
        f16x8 bl0 = *(const f16x8*)(blp + jc);
        f16x8 bl1 = *(const f16x8*)(blp + 16 * BROW + jc);
        acc0 = __builtin_amdgcn_mfma_f32_16x16x32_f16(a, bh0, acc0, 0, 0, 0);
        acc1 = __builtin_amdgcn_mfma_f32_16x16x32_f16(a, bh1, acc1, 0, 0, 0);
        acc0 = __builtin_amdgcn_mfma_f32_16x16x32_f16(a, bl0, acc0, 0, 0, 0);
        acc1 = __builtin_amdgcn_mfma_f32_16x16x32_f16(a, bl1, acc1, 0, 0, 0);
    }
    __syncthreads();                               // done reading Bh/Bl -> reuse as tl
    float* tl = (float*)Bbuf;                      // [8][32][17] floats = 17408 B
    #pragma unroll
    for (int rg = 0; rg < 4; ++rg) {
        tl[(wid * 32 + l15) * 17 + l4 * 4 + rg]      = acc0[rg];
        tl[(wid * 32 + 16 + l15) * 17 + l4 * 4 + rg] = acc1[rg];
    }
    __syncthreads();
    #pragma unroll
    for (int q = 0; q < 8; ++q) {
        int idx = q * 64 + lane;
        int t = idx >> 4, il = idx & 15;
        int gi = ib * IB + wid * 16 + il;
        float val = tl[(wid * 32 + t) * 17 + il];
        part[((size_t)jb * TT + t) * NN + gi] = val;
        if (RED) {
            float cq = r[(size_t)t * NN + gi] * val;
            #pragma unroll
            for (int o = 8; o; o >>= 1) cq += __shfl_down(cq, o);
            if (il == 0) redb[wid][t] = cq;
        }
    }
    if (RED) {
        __syncthreads();
        if (tid < 32) {
            float s = 0.f;
            #pragma unroll
            for (int u = 0; u < 8; ++u) s += redb[u][tid];
            rKvp[tid * 512 + bid] = s;
        }
    }
}

// ---------------------------------------------------------------- Chronopoulos-Gear update
// w = sum_b part + r in-register; rw = sum(rKvp) + rr. last: emit x (not r) to vh/vl.
__global__ __launch_bounds__(512) void cupd(const float* __restrict__ part, float* __restrict__ r,
                                            float* __restrict__ p, float* __restrict__ s_,
                                            float* __restrict__ x,
                                            _Float16* __restrict__ vh,
                                            _Float16* __restrict__ vl,
                                            const float* __restrict__ rrp_in,
                                            float* __restrict__ rrp_out,
                                            const float* __restrict__ rKvp,
                                            const float* __restrict__ scal_in,
                                            float* __restrict__ scal_out,
                                            int first, int last) {
    int t = blockIdx.x, c = blockIdx.y, tid = threadIdx.x;
    float rr = 0.f;
    #pragma unroll
    for (int u = 0; u < 8; ++u) rr += rrp_in[t * 8 + u];
    float rw = rr;                                 // r.w = r.Kv + r.r  (A = K+I)
    const float* rk = rKvp + t * 512;
    #pragma unroll 8
    for (int u = 0; u < 512; ++u) rw += rk[u];
    float alpha, beta;
    if (first) {
        beta = 0.f;
        alpha = rr / rw;
    } else {
        float ap = scal_in[t], rrprev = scal_in[TT + t];
        beta = rr / rrprev;
        alpha = rr / (rw - (beta / ap) * rr);
    }
    int i = c * 512 + tid;
    size_t off = (size_t)t * NN + i;
    float s = 0.f;
    #pragma unroll
    for (int b = 0; b < JBP; ++b) s += part[((size_t)b * TT + t) * NN + i];
    float rv = r[off];
    float wv = s + rv;                             // w = Kv + r
    float pn = first ? rv : fmaf(beta, p[off], rv);
    float sn = first ? wv : fmaf(beta, s_[off], wv);
    p[off] = pn; s_[off] = sn;
    float xn = x[off] + alpha * pn;
    x[off] = xn;
    float rn = rv - alpha * sn;
    r[off] = rn;
    float vout = last ? xn : rn;                   // last iter: emit x for predict matvec
    _Float16 h = (_Float16)vout;
    vh[off] = h; vl[off] = (_Float16)(vout - (float)h);
    float v = rn * rn;
    #pragma unroll
    for (int o = 32; o; o >>= 1) v += __shfl_down(v, o);
    __shared__ float red[8];
    if ((tid & 63) == 0) red[tid >> 6] = v;
    __syncthreads();
    if (tid == 0) {
        float tot = 0.f;
        #pragma unroll
        for (int u = 0; u < 8; ++u) tot += red[u];
        rrp_out[t * 8 + c] = tot;
        if (c == 0) { scal_out[t] = alpha; scal_out[TT + t] = rr; }
    }
}

// ---------------------------------------------------------------- y_pred[i][t] = sum_b part (transposed write)
__global__ __launch_bounds__(256) void predict_out(const float* __restrict__ part,
                                                   float* __restrict__ out) {
    __shared__ float st[TT][65];
    const int i0 = blockIdx.x * 64;
    const int tid = threadIdx.x;
    #pragma unroll
    for (int ph = 0; ph < 8; ++ph) {
        int idx = ph * 256 + tid;
        int il = idx & 63, t = idx >> 6;
        float s = 0.f;
        #pragma unroll
        for (int b = 0; b < JBP; ++b) s += part[((size_t)b * TT + t) * NN + i0 + il];
        st[t][il] = s;
    }
    __syncthreads();
    #pragma unroll
    for (int ph = 0; ph < 8; ++ph) {
        int idx = ph * 256 + tid;
        int t = idx & 31, il = idx >> 5;
        out[(size_t)(i0 + il) * TT + t] = st[t][il];
    }
}

extern "C" void kernel_launch(void* const* d_in, const int* in_sizes, int n_in,
                              void* d_out, int out_size, void* d_ws, size_t ws_size,
                              hipStream_t stream) {
    const float* X = (const float*)d_in[0];   // [N, D]
    const float* y = (const float*)d_in[1];   // [N, T]
    float* out = (float*)d_out;               // [N, T]

    unsigned char* wsb = (unsigned char*)d_ws;
    _Float16* Kh = (_Float16*)wsb;  wsb += (size_t)NN * NN * 2;          // 32 MB
    float* part  = (float*)wsb;     wsb += (size_t)JBP * TT * NN * 4;    // 8 MB
    float* r     = (float*)wsb;     wsb += (size_t)TT * NN * 4;
    float* p     = (float*)wsb;     wsb += (size_t)TT * NN * 4;
    float* s_    = (float*)wsb;     wsb += (size_t)TT * NN * 4;
    float* x     = (float*)wsb;     wsb += (size_t)TT * NN * 4;
    _Float16* vh = (_Float16*)wsb;  wsb += (size_t)TT * NN * 2;
    _Float16* vl = (_Float16*)wsb;  wsb += (size_t)TT * NN * 2;
    _Float16* Xh = (_Float16*)wsb;  wsb += (size_t)NN * DD * 2;          // 2 MB
    float* x2v   = (float*)wsb;     wsb += (size_t)NN * 4;
    float* rrp   = (float*)wsb;     wsb += 512 * 4;                      // 2 x 256
    float* rKvp  = (float*)wsb;     wsb += (size_t)TT * 512 * 4;         // 64 KB
    float* scal  = (float*)wsb;     wsb += 128 * 4;                      // 2 x 64

    x2conv<<<NN / 4, 256, 0, stream>>>(X, x2v, Xh);
    k_build<<<dim3(NN / 128, NN / 256), 256, 0, stream>>>(Xh, x2v, Kh);
    cg_init<<<dim3(TT, 8), 512, 0, stream>>>(y, r, x, vh, vl, rrp);

    for (int j = 0; j < ITERS; ++j) {
        matvec_part<1><<<dim3(32, JBP), 512, 0, stream>>>(Kh, vh, vl, r, part, rKvp);
        cupd<<<dim3(TT, 8), 512, 0, stream>>>(part, r, p, s_, x, vh, vl,
                                              rrp + (j & 1) * 256, rrp + ((j + 1) & 1) * 256,
                                              rKvp,
                                              scal + (j & 1) * 64, scal + ((j + 1) & 1) * 64,
                                              j == 0 ? 1 : 0, j == ITERS - 1 ? 1 : 0);
    }

    // predict: y_pred = K @ x (vh/vl hold x from the last cupd)
    matvec_part<0><<<dim3(32, JBP), 512, 0, stream>>>(Kh, vh, vl, nullptr, part, nullptr);
    predict_out<<<NN / 64, 256, 0, stream>>>(part, out);
}

// Round 10
// 204.285 us; speedup vs baseline: 8.8816x; 1.5678x over previous
//
#include <hip/hip_runtime.h>
#include <math.h>

#define NN 4096
#define DD 256
#define TT 32
#define GAMMA (1.0f/256.0f)
#define ITERS 10
#define JBP 8            // j-chunks in matvec
#define JCH 512          // j per matvec block
#define IB  128          // i-rows per matvec block
#define BROW (JCH + 8)   // padded LDS row (f16 elems): 1040 B stride
#define KB_PAD 40        // f16 elems per LDS row in k_build staging

typedef __attribute__((ext_vector_type(8))) _Float16 f16x8;
typedef __attribute__((ext_vector_type(4))) _Float16 f16x4;
typedef __attribute__((ext_vector_type(4))) float f32x4;

// ---------------------------------------------------------------- setup: x2 + f16 X; CG init
// blocks [0,1024): x2conv (4 rows each). blocks [1024,1280): cg_init (one (t,c) each).
__global__ __launch_bounds__(256) void setup(const float* __restrict__ X,
                                             float* __restrict__ x2,
                                             _Float16* __restrict__ Xh,
                                             const float* __restrict__ y,
                                             float* __restrict__ r, float* __restrict__ x,
                                             _Float16* __restrict__ vh,
                                             _Float16* __restrict__ vl,
                                             float* __restrict__ rrp) {
    const int b = blockIdx.x, tid = threadIdx.x;
    const int wid = tid >> 6, lane = tid & 63;
    if (b < 1024) {
        int row = b * 4 + wid;
        const float* xr = X + (size_t)row * DD;
        float4 v = *(const float4*)(xr + lane * 4);
        float s = v.x * v.x + v.y * v.y + v.z * v.z + v.w * v.w;
        #pragma unroll
        for (int o = 32; o; o >>= 1) s += __shfl_down(s, o);
        if (lane == 0) x2[row] = s;
        f16x4 h;
        h[0] = (_Float16)v.x; h[1] = (_Float16)v.y; h[2] = (_Float16)v.z; h[3] = (_Float16)v.w;
        *(f16x4*)(Xh + (size_t)row * DD + lane * 4) = h;
    } else {
        int bb = b - 1024;                    // 0..255
        int t = bb >> 3, c = bb & 7;
        float s = 0.f;
        #pragma unroll
        for (int pass = 0; pass < 2; ++pass) {
            int i = c * 512 + pass * 256 + tid;
            float v = y[(size_t)i * TT + t];
            size_t off = (size_t)t * NN + i;
            r[off] = v; x[off] = 0.f;
            _Float16 h = (_Float16)v;
            vh[off] = h; vl[off] = (_Float16)(v - (float)h);
            s += v * v;
        }
        #pragma unroll
        for (int o = 32; o; o >>= 1) s += __shfl_down(s, o);
        __shared__ float red[4];
        if (lane == 0) red[wid] = s;
        __syncthreads();
        if (tid == 0) rrp[t * 8 + c] = red[0] + red[1] + red[2] + red[3];
    }
}

// ---------------------------------------------------------------- K = exp(-g*d2), f16 out
// 128(i) x 256(j) tile, LDS-staged, 4 waves each 64x128 (4x8 MFMA frags).
__global__ __launch_bounds__(256) void k_build(const _Float16* __restrict__ Xh,
                                               const float* __restrict__ x2,
                                               _Float16* __restrict__ Kh) {
    __shared__ _Float16 As[128 * KB_PAD];   // 10240 B
    __shared__ _Float16 Bs[256 * KB_PAD];   // 20480 B
    const int i0 = blockIdx.x * 128, j0 = blockIdx.y * 256;
    const int tid = threadIdx.x;
    const int wid = tid >> 6, lane = tid & 63;
    const int wr = wid >> 1, wc = wid & 1;
    const int l15 = lane & 15, l4 = lane >> 4;
    f32x4 acc[4][8] = {};
    for (int kc = 0; kc < DD; kc += 32) {
        __syncthreads();
        #pragma unroll
        for (int s = 0; s < 2; ++s) {             // A: 128 rows x 4 chunks of 8
            int idx = s * 256 + tid;
            int row = idx >> 2, c = idx & 3;
            *(uint4*)(As + row * KB_PAD + c * 8) =
                *(const uint4*)(Xh + (size_t)(i0 + row) * DD + kc + c * 8);
        }
        #pragma unroll
        for (int s = 0; s < 4; ++s) {             // B: 256 rows x 4 chunks of 8
            int idx = s * 256 + tid;
            int row = idx >> 2, c = idx & 3;
            *(uint4*)(Bs + row * KB_PAD + c * 8) =
                *(const uint4*)(Xh + (size_t)(j0 + row) * DD + kc + c * 8);
        }
        __syncthreads();
        f16x8 af[4], bfr[8];
        #pragma unroll
        for (int m = 0; m < 4; ++m)
            af[m] = *(const f16x8*)(As + (wr * 64 + m * 16 + l15) * KB_PAD + l4 * 8);
        #pragma unroll
        for (int n = 0; n < 8; ++n)
            bfr[n] = *(const f16x8*)(Bs + (wc * 128 + n * 16 + l15) * KB_PAD + l4 * 8);
        #pragma unroll
        for (int m = 0; m < 4; ++m)
            #pragma unroll
            for (int n = 0; n < 8; ++n)
                acc[m][n] = __builtin_amdgcn_mfma_f32_16x16x32_f16(af[m], bfr[n], acc[m][n], 0, 0, 0);
    }
    #pragma unroll
    for (int m = 0; m < 4; ++m) {
        #pragma unroll
        for (int rg = 0; rg < 4; ++rg) {
            int i = i0 + wr * 64 + m * 16 + l4 * 4 + rg;
            float x2i = x2[i];
            #pragma unroll
            for (int n = 0; n < 8; ++n) {
                int j = j0 + wc * 128 + n * 16 + l15;
                float d2 = fmaxf(x2i + x2[j] - 2.f * acc[m][n][rg], 0.f);
                Kh[(size_t)i * NN + j] = (_Float16)__expf(-GAMMA * d2);
            }
        }
    }
}

// ---------------------------------------------------------------- matvec: part[jb][t][i] = sum_{j in jb} K[i][j]*v[t][j]
// Block = 128 i-rows (8 waves x 16) x 512 j. v (hi/lo) staged in LDS.
// RED=1: also emit rKvp[t][bid] = sum_{i in blk} r[t][i] * (Kv)[t][i]
template<int RED>
__global__ __launch_bounds__(512) void matvec_part(const _Float16* __restrict__ Kh,
                                                   const _Float16* __restrict__ vh,
                                                   const _Float16* __restrict__ vl,
                                                   const float* __restrict__ r,
                                                   float* __restrict__ part,
                                                   float* __restrict__ rKvp) {
    __shared__ __align__(16) _Float16 Bbuf[2 * 32 * BROW];   // 66560 B (hi | lo)
    __shared__ float redb[8][33];
    _Float16* Bh = Bbuf;
    _Float16* Bl = Bbuf + 32 * BROW;
    const int ib = blockIdx.x;                    // 32
    const int jb = blockIdx.y;                    // 8
    const int bid = jb * 32 + ib;                 // 0..255
    const int tid = threadIdx.x;
    const int wid = tid >> 6, lane = tid & 63;
    const int l15 = lane & 15, l4 = lane >> 4;
    // stage v: 32 t-rows x 512 j, hi and lo
    #pragma unroll
    for (int s = 0; s < 4; ++s) {
        int c = s * 512 + tid;                    // 2048 chunks of 8 f16
        int row = c >> 6, col8 = c & 63;
        *(uint4*)(Bh + row * BROW + col8 * 8) =
            *(const uint4*)(vh + (size_t)row * NN + jb * JCH + col8 * 8);
        *(uint4*)(Bl + row * BROW + col8 * 8) =
            *(const uint4*)(vl + (size_t)row * NN + jb * JCH + col8 * 8);
    }
    __syncthreads();
    const _Float16* Ap  = Kh + (size_t)(ib * IB + wid * 16 + l15) * NN + jb * JCH + l4 * 8;
    const _Float16* bhp = Bh + l15 * BROW + l4 * 8;
    const _Float16* blp = Bl + l15 * BROW + l4 * 8;
    f32x4 acc0 = {}, acc1 = {};
    #pragma unroll 4
    for (int jc = 0; jc < JCH; jc += 32) {
        f16x8 a   = *(const f16x8*)(Ap + jc);
        f16x8 bh0 = *(const f16x8*)(bhp + jc);
        f16x8 bh1 = *(const f16x8*)(bhp + 16 * BROW + jc);
        f16x8 bl0 = *(const f16x8*)(blp + jc);
        f16x8 bl1 = *(const f16x8*)(blp + 16 * BROW + jc);
        acc0 = __builtin_amdgcn_mfma_f32_16x16x32_f16(a, bh0, acc0, 0, 0, 0);
        acc1 = __builtin_amdgcn_mfma_f32_16x16x32_f16(a, bh1, acc1, 0, 0, 0);
        acc0 = __builtin_amdgcn_mfma_f32_16x16x32_f16(a, bl0, acc0, 0, 0, 0);
        acc1 = __builtin_amdgcn_mfma_f32_16x16x32_f16(a, bl1, acc1, 0, 0, 0);
    }
    __syncthreads();                               // done reading Bh/Bl -> reuse as tl
    float* tl = (float*)Bbuf;                      // [8][32][17] floats = 17408 B
    #pragma unroll
    for (int rg = 0; rg < 4; ++rg) {
        tl[(wid * 32 + l15) * 17 + l4 * 4 + rg]      = acc0[rg];
        tl[(wid * 32 + 16 + l15) * 17 + l4 * 4 + rg] = acc1[rg];
    }
    __syncthreads();
    #pragma unroll
    for (int q = 0; q < 8; ++q) {
        int idx = q * 64 + lane;
        int t = idx >> 4, il = idx & 15;
        int gi = ib * IB + wid * 16 + il;
        float val = tl[(wid * 32 + t) * 17 + il];
        part[((size_t)jb * TT + t) * NN + gi] = val;
        if (RED) {
            float cq = r[(size_t)t * NN + gi] * val;
            #pragma unroll
            for (int o = 8; o; o >>= 1) cq += __shfl_down(cq, o);
            if (il == 0) redb[wid][t] = cq;
        }
    }
    if (RED) {
        __syncthreads();
        if (tid < 32) {
            float s = 0.f;
            #pragma unroll
            for (int u = 0; u < 8; ++u) s += redb[u][tid];
            rKvp[tid * 256 + bid] = s;
        }
    }
}

// ---------------------------------------------------------------- Chronopoulos-Gear update
// Scalars computed by wave 0 (parallel reduce of 256 partials), LDS-broadcast.
// w = sum_b part + r in-register; rw = sum(rKvp) + rr. last: emit x (not r) to vh/vl.
__global__ __launch_bounds__(512) void cupd(const float* __restrict__ part, float* __restrict__ r,
                                            float* __restrict__ p, float* __restrict__ s_,
                                            float* __restrict__ x,
                                            _Float16* __restrict__ vh,
                                            _Float16* __restrict__ vl,
                                            const float* __restrict__ rrp_in,
                                            float* __restrict__ rrp_out,
                                            const float* __restrict__ rKvp,
                                            const float* __restrict__ scal_in,
                                            float* __restrict__ scal_out,
                                            int first, int last) {
    const int t = blockIdx.x, c = blockIdx.y, tid = threadIdx.x;
    const int wid = tid >> 6, lane = tid & 63;
    __shared__ float sc2[2];
    __shared__ float red[8];
    if (wid == 0) {
        float rw_ = 0.f;
        #pragma unroll
        for (int u = 0; u < 4; ++u) rw_ += rKvp[t * 256 + u * 64 + lane];
        float rr_ = (lane < 8) ? rrp_in[t * 8 + lane] : 0.f;
        #pragma unroll
        for (int o = 32; o; o >>= 1) { rw_ += __shfl_down(rw_, o); rr_ += __shfl_down(rr_, o); }
        if (lane == 0) {
            float rr = rr_;
            float rw = rw_ + rr;                   // r.w = r.Kv + r.r  (A = K+I)
            float alpha, beta;
            if (first) { beta = 0.f; alpha = rr / rw; }
            else {
                float ap = scal_in[t], rrprev = scal_in[TT + t];
                beta = rr / rrprev;
                alpha = rr / (rw - (beta / ap) * rr);
            }
            sc2[0] = alpha; sc2[1] = beta;
            if (c == 0) { scal_out[t] = alpha; scal_out[TT + t] = rr; }
        }
    }
    __syncthreads();
    const float alpha = sc2[0], beta = sc2[1];
    int i = c * 512 + tid;
    size_t off = (size_t)t * NN + i;
    float s = 0.f;
    #pragma unroll
    for (int b = 0; b < JBP; ++b) s += part[((size_t)b * TT + t) * NN + i];
    float rv = r[off];
    float wv = s + rv;                             // w = Kv + r
    float pn = first ? rv : fmaf(beta, p[off], rv);
    float sn = first ? wv : fmaf(beta, s_[off], wv);
    p[off] = pn; s_[off] = sn;
    float xn = x[off] + alpha * pn;
    x[off] = xn;
    float rn = rv - alpha * sn;
    r[off] = rn;
    float vout = last ? xn : rn;                   // last iter: emit x for predict matvec
    _Float16 h = (_Float16)vout;
    vh[off] = h; vl[off] = (_Float16)(vout - (float)h);
    float v = rn * rn;
    #pragma unroll
    for (int o = 32; o; o >>= 1) v += __shfl_down(v, o);
    if (lane == 0) red[wid] = v;
    __syncthreads();
    if (tid == 0) {
        float tot = 0.f;
        #pragma unroll
        for (int u = 0; u < 8; ++u) tot += red[u];
        rrp_out[t * 8 + c] = tot;
    }
}

// ---------------------------------------------------------------- y_pred[i][t] = sum_b part (transposed write)
__global__ __launch_bounds__(256) void predict_out(const float* __restrict__ part,
                                                   float* __restrict__ out) {
    __shared__ float st[TT][65];
    const int i0 = blockIdx.x * 64;
    const int tid = threadIdx.x;
    #pragma unroll
    for (int ph = 0; ph < 8; ++ph) {
        int idx = ph * 256 + tid;
        int il = idx & 63, t = idx >> 6;
        float s = 0.f;
        #pragma unroll
        for (int b = 0; b < JBP; ++b) s += part[((size_t)b * TT + t) * NN + i0 + il];
        st[t][il] = s;
    }
    __syncthreads();
    #pragma unroll
    for (int ph = 0; ph < 8; ++ph) {
        int idx = ph * 256 + tid;
        int t = idx & 31, il = idx >> 5;
        out[(size_t)(i0 + il) * TT + t] = st[t][il];
    }
}

extern "C" void kernel_launch(void* const* d_in, const int* in_sizes, int n_in,
                              void* d_out, int out_size, void* d_ws, size_t ws_size,
                              hipStream_t stream) {
    const float* X = (const float*)d_in[0];   // [N, D]
    const float* y = (const float*)d_in[1];   // [N, T]
    float* out = (float*)d_out;               // [N, T]

    unsigned char* wsb = (unsigned char*)d_ws;
    _Float16* Kh = (_Float16*)wsb;  wsb += (size_t)NN * NN * 2;          // 32 MB
    float* part  = (float*)wsb;     wsb += (size_t)JBP * TT * NN * 4;    // 4 MB
    float* r     = (float*)wsb;     wsb += (size_t)TT * NN * 4;
    float* p     = (float*)wsb;     wsb += (size_t)TT * NN * 4;
    float* s_    = (float*)wsb;     wsb += (size_t)TT * NN * 4;
    float* x     = (float*)wsb;     wsb += (size_t)TT * NN * 4;
    _Float16* vh = (_Float16*)wsb;  wsb += (size_t)TT * NN * 2;
    _Float16* vl = (_Float16*)wsb;  wsb += (size_t)TT * NN * 2;
    _Float16* Xh = (_Float16*)wsb;  wsb += (size_t)NN * DD * 2;          // 2 MB
    float* x2v   = (float*)wsb;     wsb += (size_t)NN * 4;
    float* rrp   = (float*)wsb;     wsb += 512 * 4;                      // 2 x 256
    float* rKvp  = (float*)wsb;     wsb += (size_t)TT * 256 * 4;         // 32 KB
    float* scal  = (float*)wsb;     wsb += 128 * 4;                      // 2 x 64

    setup<<<1280, 256, 0, stream>>>(X, x2v, Xh, y, r, x, vh, vl, rrp);
    k_build<<<dim3(NN / 128, NN / 256), 256, 0, stream>>>(Xh, x2v, Kh);

    for (int j = 0; j < ITERS; ++j) {
        matvec_part<1><<<dim3(32, JBP), 512, 0, stream>>>(Kh, vh, vl, r, part, rKvp);
        cupd<<<dim3(TT, 8), 512, 0, stream>>>(part, r, p, s_, x, vh, vl,
                                              rrp + (j & 1) * 256, rrp + ((j + 1) & 1) * 256,
                                              rKvp,
                                              scal + (j & 1) * 64, scal + ((j + 1) & 1) * 64,
                                              j == 0 ? 1 : 0, j == ITERS - 1 ? 1 : 0);
    }

    // predict: y_pred = K @ x (vh/vl hold x from the last cupd)
    matvec_part<0><<<dim3(32, JBP), 512, 0, stream>>>(Kh, vh, vl, nullptr, part, nullptr);
    predict_out<<<NN / 64, 256, 0, stream>>>(part, out);
}

// Round 11
// 191.814 us; speedup vs baseline: 9.4590x; 1.0650x over previous
//
#include <hip/hip_runtime.h>
#include <math.h>

#define NN 4096
#define DD 256
#define TT 32
#define GAMMA (1.0f/256.0f)
#define ITERS 10
#define JBP 8            // j-chunks in matvec
#define JCH 512          // j per matvec block
#define IB  128          // i-rows per matvec block
#define BROW (JCH + 8)   // padded LDS row (f16 elems): 1040 B stride
#define KC  64           // k-chunk in k_build
#define KBP 72           // f16 elems per LDS row in k_build staging (64 + 8 pad)

typedef __attribute__((ext_vector_type(8))) _Float16 f16x8;
typedef __attribute__((ext_vector_type(4))) _Float16 f16x4;
typedef __attribute__((ext_vector_type(4))) float f32x4;

// ---------------------------------------------------------------- setup: x2 + f16 X; CG init
// blocks [0,1024): x2conv (4 rows each). blocks [1024,1280): cg_init (one (t,c) each).
__global__ __launch_bounds__(256) void setup(const float* __restrict__ X,
                                             float* __restrict__ x2,
                                             _Float16* __restrict__ Xh,
                                             const float* __restrict__ y,
                                             float* __restrict__ r,
                                             _Float16* __restrict__ vh,
                                             _Float16* __restrict__ vl,
                                             float* __restrict__ rrp) {
    const int b = blockIdx.x, tid = threadIdx.x;
    const int wid = tid >> 6, lane = tid & 63;
    if (b < 1024) {
        int row = b * 4 + wid;
        const float* xr = X + (size_t)row * DD;
        float4 v = *(const float4*)(xr + lane * 4);
        float s = v.x * v.x + v.y * v.y + v.z * v.z + v.w * v.w;
        #pragma unroll
        for (int o = 32; o; o >>= 1) s += __shfl_down(s, o);
        if (lane == 0) x2[row] = s;
        f16x4 h;
        h[0] = (_Float16)v.x; h[1] = (_Float16)v.y; h[2] = (_Float16)v.z; h[3] = (_Float16)v.w;
        *(f16x4*)(Xh + (size_t)row * DD + lane * 4) = h;
    } else {
        int bb = b - 1024;                    // 0..255
        int t = bb >> 3, c = bb & 7;
        float s = 0.f;
        #pragma unroll
        for (int pass = 0; pass < 2; ++pass) {
            int i = c * 512 + pass * 256 + tid;
            float v = y[(size_t)i * TT + t];
            size_t off = (size_t)t * NN + i;
            r[off] = v;
            _Float16 h = (_Float16)v;
            vh[off] = h; vl[off] = (_Float16)(v - (float)h);
            s += v * v;
        }
        #pragma unroll
        for (int o = 32; o; o >>= 1) s += __shfl_down(s, o);
        __shared__ float red[4];
        if (lane == 0) red[wid] = s;
        __syncthreads();
        if (tid == 0) rrp[t * 8 + c] = red[0] + red[1] + red[2] + red[3];
    }
}

// ---------------------------------------------------------------- K = exp(-g*d2), f16 out
// 128(i) x 256(j) tile, KC=64 staging (8 barriers total), 4 waves each 64x128.
__global__ __launch_bounds__(256) void k_build(const _Float16* __restrict__ Xh,
                                               const float* __restrict__ x2,
                                               _Float16* __restrict__ Kh) {
    __shared__ _Float16 As[128 * KBP];   // 18432 B
    __shared__ _Float16 Bs[256 * KBP];   // 36864 B
    const int i0 = blockIdx.x * 128, j0 = blockIdx.y * 256;
    const int tid = threadIdx.x;
    const int wid = tid >> 6, lane = tid & 63;
    const int wr = wid >> 1, wc = wid & 1;
    const int l15 = lane & 15, l4 = lane >> 4;
    f32x4 acc[4][8] = {};
    for (int kc = 0; kc < DD; kc += KC) {
        __syncthreads();
        #pragma unroll
        for (int s = 0; s < 4; ++s) {             // A: 128 rows x 8 chunks of 8
            int idx = s * 256 + tid;
            int row = idx >> 3, c = idx & 7;
            *(uint4*)(As + row * KBP + c * 8) =
                *(const uint4*)(Xh + (size_t)(i0 + row) * DD + kc + c * 8);
        }
        #pragma unroll
        for (int s = 0; s < 8; ++s) {             // B: 256 rows x 8 chunks of 8
            int idx = s * 256 + tid;
            int row = idx >> 3, c = idx & 7;
            *(uint4*)(Bs + row * KBP + c * 8) =
                *(const uint4*)(Xh + (size_t)(j0 + row) * DD + kc + c * 8);
        }
        __syncthreads();
        #pragma unroll
        for (int kk = 0; kk < 2; ++kk) {
            f16x8 af[4], bfr[8];
            #pragma unroll
            for (int m = 0; m < 4; ++m)
                af[m] = *(const f16x8*)(As + (wr * 64 + m * 16 + l15) * KBP + kk * 32 + l4 * 8);
            #pragma unroll
            for (int n = 0; n < 8; ++n)
                bfr[n] = *(const f16x8*)(Bs + (wc * 128 + n * 16 + l15) * KBP + kk * 32 + l4 * 8);
            #pragma unroll
            for (int m = 0; m < 4; ++m)
                #pragma unroll
                for (int n = 0; n < 8; ++n)
                    acc[m][n] = __builtin_amdgcn_mfma_f32_16x16x32_f16(af[m], bfr[n], acc[m][n], 0, 0, 0);
        }
    }
    #pragma unroll
    for (int m = 0; m < 4; ++m) {
        #pragma unroll
        for (int rg = 0; rg < 4; ++rg) {
            int i = i0 + wr * 64 + m * 16 + l4 * 4 + rg;
            float x2i = x2[i];
            #pragma unroll
            for (int n = 0; n < 8; ++n) {
                int j = j0 + wc * 128 + n * 16 + l15;
                float d2 = fmaxf(x2i + x2[j] - 2.f * acc[m][n][rg], 0.f);
                Kh[(size_t)i * NN + j] = (_Float16)__expf(-GAMMA * d2);
            }
        }
    }
}

// ---------------------------------------------------------------- matvec: part[jb][t][i] = sum_{j in jb} K[i][j]*v[t][j]
// Block = 128 i-rows (8 waves x 16) x 512 j. v (hi/lo) staged in LDS.
// Also emits rKvp[t][bid] = sum_{i in blk} r[t][i] * (Kv)[t][i]
__global__ __launch_bounds__(512) void matvec_part(const _Float16* __restrict__ Kh,
                                                   const _Float16* __restrict__ vh,
                                                   const _Float16* __restrict__ vl,
                                                   const float* __restrict__ r,
                                                   float* __restrict__ part,
                                                   float* __restrict__ rKvp) {
    __shared__ __align__(16) _Float16 Bbuf[2 * 32 * BROW];   // 66560 B (hi | lo)
    __shared__ float redb[8][33];
    _Float16* Bh = Bbuf;
    _Float16* Bl = Bbuf + 32 * BROW;
    const int ib = blockIdx.x;                    // 32
    const int jb = blockIdx.y;                    // 8
    const int bid = jb * 32 + ib;                 // 0..255
    const int tid = threadIdx.x;
    const int wid = tid >> 6, lane = tid & 63;
    const int l15 = lane & 15, l4 = lane >> 4;
    // stage v: 32 t-rows x 512 j, hi and lo
    #pragma unroll
    for (int s = 0; s < 4; ++s) {
        int c = s * 512 + tid;                    // 2048 chunks of 8 f16
        int row = c >> 6, col8 = c & 63;
        *(uint4*)(Bh + row * BROW + col8 * 8) =
            *(const uint4*)(vh + (size_t)row * NN + jb * JCH + col8 * 8);
        *(uint4*)(Bl + row * BROW + col8 * 8) =
            *(const uint4*)(vl + (size_t)row * NN + jb * JCH + col8 * 8);
    }
    __syncthreads();
    const _Float16* Ap  = Kh + (size_t)(ib * IB + wid * 16 + l15) * NN + jb * JCH + l4 * 8;
    const _Float16* bhp = Bh + l15 * BROW + l4 * 8;
    const _Float16* blp = Bl + l15 * BROW + l4 * 8;
    f32x4 acc0 = {}, acc1 = {};
    #pragma unroll 4
    for (int jc = 0; jc < JCH; jc += 32) {
        f16x8 a   = *(const f16x8*)(Ap + jc);
        f16x8 bh0 = *(const f16x8*)(bhp + jc);
        f16x8 bh1 = *(const f16x8*)(bhp + 16 * BROW + jc);
        f16x8 bl0 = *(const f16x8*)(blp + jc);
        f16x8 bl1 = *(const f16x8*)(blp + 16 * BROW + jc);
        acc0 = __builtin_amdgcn_mfma_f32_16x16x32_f16(a, bh0, acc0, 0, 0, 0);
        acc1 = __builtin_amdgcn_mfma_f32_16x16x32_f16(a, bh1, acc1, 0, 0, 0);
        acc0 = __builtin_amdgcn_mfma_f32_16x16x32_f16(a, bl0, acc0, 0, 0, 0);
        acc1 = __builtin_amdgcn_mfma_f32_16x16x32_f16(a, bl1, acc1, 0, 0, 0);
    }
    __syncthreads();                               // done reading Bh/Bl -> reuse as tl
    float* tl = (float*)Bbuf;                      // [8][32][17] floats = 17408 B
    #pragma unroll
    for (int rg = 0; rg < 4; ++rg) {
        tl[(wid * 32 + l15) * 17 + l4 * 4 + rg]      = acc0[rg];
        tl[(wid * 32 + 16 + l15) * 17 + l4 * 4 + rg] = acc1[rg];
    }
    __syncthreads();
    #pragma unroll
    for (int q = 0; q < 8; ++q) {
        int idx = q * 64 + lane;
        int t = idx >> 4, il = idx & 15;
        int gi = ib * IB + wid * 16 + il;
        float val = tl[(wid * 32 + t) * 17 + il];
        part[((size_t)jb * TT + t) * NN + gi] = val;
        float cq = r[(size_t)t * NN + gi] * val;
        #pragma unroll
        for (int o = 8; o; o >>= 1) cq += __shfl_down(cq, o);
        if (il == 0) redb[wid][t] = cq;
    }
    __syncthreads();
    if (tid < 32) {
        float s = 0.f;
        #pragma unroll
        for (int u = 0; u < 8; ++u) s += redb[u][tid];
        rKvp[tid * 256 + bid] = s;
    }
}

// ---------------------------------------------------------------- Chronopoulos-Gear update
// Scalars by wave 0 (parallel reduce), LDS-broadcast. Tracks ax = A@x via ax += alpha*s.
// last: out[i][t] = ax_new - x_new  (y_pred = K@x = A@x - x). No predict matvec needed.
__global__ __launch_bounds__(512) void cupd(const float* __restrict__ part, float* __restrict__ r,
                                            float* __restrict__ p, float* __restrict__ s_,
                                            float* __restrict__ x, float* __restrict__ ax,
                                            _Float16* __restrict__ vh,
                                            _Float16* __restrict__ vl,
                                            const float* __restrict__ rrp_in,
                                            float* __restrict__ rrp_out,
                                            const float* __restrict__ rKvp,
                                            const float* __restrict__ scal_in,
                                            float* __restrict__ scal_out,
                                            float* __restrict__ out,
                                            int first, int last) {
    const int t = blockIdx.x, c = blockIdx.y, tid = threadIdx.x;
    const int wid = tid >> 6, lane = tid & 63;
    __shared__ float sc2[2];
    __shared__ float red[8];
    if (wid == 0) {
        float rw_ = 0.f;
        #pragma unroll
        for (int u = 0; u < 4; ++u) rw_ += rKvp[t * 256 + u * 64 + lane];
        float rr_ = (lane < 8) ? rrp_in[t * 8 + lane] : 0.f;
        #pragma unroll
        for (int o = 32; o; o >>= 1) { rw_ += __shfl_down(rw_, o); rr_ += __shfl_down(rr_, o); }
        if (lane == 0) {
            float rr = rr_;
            float rw = rw_ + rr;                   // r.w = r.Kv + r.r  (A = K+I)
            float alpha, beta;
            if (first) { beta = 0.f; alpha = rr / rw; }
            else {
                float ap = scal_in[t], rrprev = scal_in[TT + t];
                beta = rr / rrprev;
                alpha = rr / (rw - (beta / ap) * rr);
            }
            sc2[0] = alpha; sc2[1] = beta;
            if (c == 0) { scal_out[t] = alpha; scal_out[TT + t] = rr; }
        }
    }
    __syncthreads();
    const float alpha = sc2[0], beta = sc2[1];
    int i = c * 512 + tid;
    size_t off = (size_t)t * NN + i;
    float s = 0.f;
    #pragma unroll
    for (int b = 0; b < JBP; ++b) s += part[((size_t)b * TT + t) * NN + i];
    float rv = r[off];
    float wv = s + rv;                             // w = Kv + r
    float pn = first ? rv : fmaf(beta, p[off], rv);
    float sn = first ? wv : fmaf(beta, s_[off], wv);
    p[off] = pn; s_[off] = sn;
    float xn  = (first ? 0.f : x[off])  + alpha * pn;
    float axn = (first ? 0.f : ax[off]) + alpha * sn;
    x[off] = xn; ax[off] = axn;
    float rn = rv - alpha * sn;
    r[off] = rn;
    if (last) {
        out[(size_t)i * TT + t] = axn - xn;        // y_pred = A@x - x = K@x
    } else {
        _Float16 h = (_Float16)rn;
        vh[off] = h; vl[off] = (_Float16)(rn - (float)h);
    }
    float v = rn * rn;
    #pragma unroll
    for (int o = 32; o; o >>= 1) v += __shfl_down(v, o);
    if (lane == 0) red[wid] = v;
    __syncthreads();
    if (tid == 0) {
        float tot = 0.f;
        #pragma unroll
        for (int u = 0; u < 8; ++u) tot += red[u];
        rrp_out[t * 8 + c] = tot;
    }
}

extern "C" void kernel_launch(void* const* d_in, const int* in_sizes, int n_in,
                              void* d_out, int out_size, void* d_ws, size_t ws_size,
                              hipStream_t stream) {
    const float* X = (const float*)d_in[0];   // [N, D]
    const float* y = (const float*)d_in[1];   // [N, T]
    float* out = (float*)d_out;               // [N, T]

    unsigned char* wsb = (unsigned char*)d_ws;
    _Float16* Kh = (_Float16*)wsb;  wsb += (size_t)NN * NN * 2;          // 32 MB
    float* part  = (float*)wsb;     wsb += (size_t)JBP * TT * NN * 4;    // 4 MB
    float* r     = (float*)wsb;     wsb += (size_t)TT * NN * 4;
    float* p     = (float*)wsb;     wsb += (size_t)TT * NN * 4;
    float* s_    = (float*)wsb;     wsb += (size_t)TT * NN * 4;
    float* x     = (float*)wsb;     wsb += (size_t)TT * NN * 4;
    float* ax    = (float*)wsb;     wsb += (size_t)TT * NN * 4;
    _Float16* vh = (_Float16*)wsb;  wsb += (size_t)TT * NN * 2;
    _Float16* vl = (_Float16*)wsb;  wsb += (size_t)TT * NN * 2;
    _Float16* Xh = (_Float16*)wsb;  wsb += (size_t)NN * DD * 2;          // 2 MB
    float* x2v   = (float*)wsb;     wsb += (size_t)NN * 4;
    float* rrp   = (float*)wsb;     wsb += 512 * 4;                      // 2 x 256
    float* rKvp  = (float*)wsb;     wsb += (size_t)TT * 256 * 4;         // 32 KB
    float* scal  = (float*)wsb;     wsb += 128 * 4;                      // 2 x 64

    setup<<<1280, 256, 0, stream>>>(X, x2v, Xh, y, r, vh, vl, rrp);
    k_build<<<dim3(NN / 128, NN / 256), 256, 0, stream>>>(Xh, x2v, Kh);

    for (int j = 0; j < ITERS; ++j) {
        matvec_part<<<dim3(32, JBP), 512, 0, stream>>>(Kh, vh, vl, r, part, rKvp);
        cupd<<<dim3(TT, 8), 512, 0, stream>>>(part, r, p, s_, x, ax, vh, vl,
                                              rrp + (j & 1) * 256, rrp + ((j + 1) & 1) * 256,
                                              rKvp,
                                              scal + (j & 1) * 64, scal + ((j + 1) & 1) * 64,
                                              out,
                                              j == 0 ? 1 : 0, j == ITERS - 1 ? 1 : 0);
    }
}

// Round 13
// 187.834 us; speedup vs baseline: 9.6595x; 1.0212x over previous
//
#include <hip/hip_runtime.h>
#include <math.h>

#define NN 4096
#define DD 256
#define TT 32
#define GAMMA (1.0f/256.0f)
#define ITERS 10
#define JBP 8            // j-chunks in matvec
#define JCH 512          // j per matvec block
#define IB  64           // i-rows per matvec block (4 waves)
#define BROW (JCH + 8)   // padded LDS row (f16 elems): 1040 B stride
#define KC  64           // k-chunk in k_build
#define KBP 72           // f16 elems per LDS row in k_build staging (64 + 8 pad)

typedef __attribute__((ext_vector_type(8))) _Float16 f16x8;
typedef __attribute__((ext_vector_type(4))) _Float16 f16x4;
typedef __attribute__((ext_vector_type(2))) _Float16 f16x2;
typedef __attribute__((ext_vector_type(4))) float f32x4;

// ---------------------------------------------------------------- setup: x2 + f16 X; CG init
// blocks [0,1024): x2conv (4 rows each). blocks [1024,1152): cg_init (one (t,c) each, c in 0..3).
__global__ __launch_bounds__(256) void setup(const float* __restrict__ X,
                                             float* __restrict__ x2,
                                             _Float16* __restrict__ Xh,
                                             const float* __restrict__ y,
                                             float* __restrict__ r,
                                             _Float16* __restrict__ vh,
                                             _Float16* __restrict__ vl,
                                             float* __restrict__ rrp) {
    const int b = blockIdx.x, tid = threadIdx.x;
    const int wid = tid >> 6, lane = tid & 63;
    if (b < 1024) {
        int row = b * 4 + wid;
        const float* xr = X + (size_t)row * DD;
        float4 v = *(const float4*)(xr + lane * 4);
        float s = v.x * v.x + v.y * v.y + v.z * v.z + v.w * v.w;
        #pragma unroll
        for (int o = 32; o; o >>= 1) s += __shfl_down(s, o);
        if (lane == 0) x2[row] = s;
        f16x4 h;
        h[0] = (_Float16)v.x; h[1] = (_Float16)v.y; h[2] = (_Float16)v.z; h[3] = (_Float16)v.w;
        *(f16x4*)(Xh + (size_t)row * DD + lane * 4) = h;
    } else {
        int bb = b - 1024;                    // 0..127
        int t = bb >> 2, c = bb & 3;          // 4 rr-partials per t (matches cupd grid.y = 4)
        float s = 0.f;
        #pragma unroll
        for (int pass = 0; pass < 4; ++pass) {
            int i = c * 1024 + pass * 256 + tid;
            float v = y[(size_t)i * TT + t];
            size_t off = (size_t)t * NN + i;
            r[off] = v;
            _Float16 h = (_Float16)v;
            vh[off] = h; vl[off] = (_Float16)(v - (float)h);
            s += v * v;
        }
        #pragma unroll
        for (int o = 32; o; o >>= 1) s += __shfl_down(s, o);
        __shared__ float red[4];
        if (lane == 0) red[wid] = s;
        __syncthreads();
        if (tid == 0) rrp[t * 4 + c] = red[0] + red[1] + red[2] + red[3];
    }
}

// ---------------------------------------------------------------- K = exp(-g*d2), f16 out
// 256(i) x 256(j) tile, 8 waves (2x4), wave tile 128x64. KC=64 staging.
__global__ __launch_bounds__(512) void k_build(const _Float16* __restrict__ Xh,
                                               const float* __restrict__ x2,
                                               _Float16* __restrict__ Kh) {
    __shared__ _Float16 As[256 * KBP];   // 36864 B
    __shared__ _Float16 Bs[256 * KBP];   // 36864 B
    const int i0 = blockIdx.x * 256, j0 = blockIdx.y * 256;
    const int tid = threadIdx.x;
    const int wid = tid >> 6, lane = tid & 63;
    const int wr = wid >> 2, wc = wid & 3;         // 2 x 4 waves, 128 x 64 each
    const int l15 = lane & 15, l4 = lane >> 4;
    f32x4 acc[8][4] = {};
    for (int kc = 0; kc < DD; kc += KC) {
        __syncthreads();
        #pragma unroll
        for (int s = 0; s < 4; ++s) {             // A: 256 rows x 8 chunks of 8
            int idx = s * 512 + tid;
            int row = idx >> 3, c = idx & 7;
            *(uint4*)(As + row * KBP + c * 8) =
                *(const uint4*)(Xh + (size_t)(i0 + row) * DD + kc + c * 8);
        }
        #pragma unroll
        for (int s = 0; s < 4; ++s) {             // B: 256 rows x 8 chunks of 8
            int idx = s * 512 + tid;
            int row = idx >> 3, c = idx & 7;
            *(uint4*)(Bs + row * KBP + c * 8) =
                *(const uint4*)(Xh + (size_t)(j0 + row) * DD + kc + c * 8);
        }
        __syncthreads();
        #pragma unroll
        for (int kk = 0; kk < 2; ++kk) {
            f16x8 af[8], bfr[4];
            #pragma unroll
            for (int m = 0; m < 8; ++m)
                af[m] = *(const f16x8*)(As + (wr * 128 + m * 16 + l15) * KBP + kk * 32 + l4 * 8);
            #pragma unroll
            for (int n = 0; n < 4; ++n)
                bfr[n] = *(const f16x8*)(Bs + (wc * 64 + n * 16 + l15) * KBP + kk * 32 + l4 * 8);
            #pragma unroll
            for (int m = 0; m < 8; ++m)
                #pragma unroll
                for (int n = 0; n < 4; ++n)
                    acc[m][n] = __builtin_amdgcn_mfma_f32_16x16x32_f16(af[m], bfr[n], acc[m][n], 0, 0, 0);
        }
    }
    #pragma unroll
    for (int m = 0; m < 8; ++m) {
        #pragma unroll
        for (int rg = 0; rg < 4; ++rg) {
            int i = i0 + wr * 128 + m * 16 + l4 * 4 + rg;
            float x2i = x2[i];
            #pragma unroll
            for (int n = 0; n < 4; ++n) {
                int j = j0 + wc * 64 + n * 16 + l15;
                float d2 = fmaxf(x2i + x2[j] - 2.f * acc[m][n][rg], 0.f);
                Kh[(size_t)i * NN + j] = (_Float16)__expf(-GAMMA * d2);
            }
        }
    }
}

// ---------------------------------------------------------------- matvec: part[jb][t][i] = sum_{j in jb} K[i][j]*v[t][j]
// Block = 64 i-rows (4 waves x 16) x 512 j; grid (64,8) = 512 blocks -> 2 blocks/CU.
// Also emits rKvp[t][bid] = sum_{i in blk} r[t][i] * (Kv)[t][i]
__global__ __launch_bounds__(256) void matvec_part(const _Float16* __restrict__ Kh,
                                                   const _Float16* __restrict__ vh,
                                                   const _Float16* __restrict__ vl,
                                                   const float* __restrict__ r,
                                                   float* __restrict__ part,
                                                   float* __restrict__ rKvp) {
    __shared__ __align__(16) _Float16 Bbuf[2 * 32 * BROW];   // 66560 B (hi | lo)
    __shared__ float redb[4][33];
    _Float16* Bh = Bbuf;
    _Float16* Bl = Bbuf + 32 * BROW;
    const int ib = blockIdx.x;                    // 64
    const int jb = blockIdx.y;                    // 8
    const int bid = jb * 64 + ib;                 // 0..511
    const int tid = threadIdx.x;
    const int wid = tid >> 6, lane = tid & 63;
    const int l15 = lane & 15, l4 = lane >> 4;
    // stage v: 32 t-rows x 512 j, hi and lo
    #pragma unroll
    for (int s = 0; s < 8; ++s) {
        int c = s * 256 + tid;                    // 2048 chunks of 8 f16
        int row = c >> 6, col8 = c & 63;
        *(uint4*)(Bh + row * BROW + col8 * 8) =
            *(const uint4*)(vh + (size_t)row * NN + jb * JCH + col8 * 8);
        *(uint4*)(Bl + row * BROW + col8 * 8) =
            *(const uint4*)(vl + (size_t)row * NN + jb * JCH + col8 * 8);
    }
    __syncthreads();
    const _Float16* Ap  = Kh + (size_t)(ib * IB + wid * 16 + l15) * NN + jb * JCH + l4 * 8;
    const _Float16* bhp = Bh + l15 * BROW + l4 * 8;
    const _Float16* blp = Bl + l15 * BROW + l4 * 8;
    f32x4 acc0 = {}, acc1 = {};
    #pragma unroll 4
    for (int jc = 0; jc < JCH; jc += 32) {
        f16x8 a   = *(const f16x8*)(Ap + jc);
        f16x8 bh0 = *(const f16x8*)(bhp + jc);
        f16x8 bh1 = *(const f16x8*)(bhp + 16 * BROW + jc);
        f16x8 bl0 = *(const f16x8*)(blp + jc);
        f16x8 bl1 = *(const f16x8*)(blp + 16 * BROW + jc);
        acc0 = __builtin_amdgcn_mfma_f32_16x16x32_f16(a, bh0, acc0, 0, 0, 0);
        acc1 = __builtin_amdgcn_mfma_f32_16x16x32_f16(a, bh1, acc1, 0, 0, 0);
        acc0 = __builtin_amdgcn_mfma_f32_16x16x32_f16(a, bl0, acc0, 0, 0, 0);
        acc1 = __builtin_amdgcn_mfma_f32_16x16x32_f16(a, bl1, acc1, 0, 0, 0);
    }
    __syncthreads();                               // done reading Bh/Bl -> reuse as tl
    float* tl = (float*)Bbuf;                      // [4][32][17] floats
    #pragma unroll
    for (int rg = 0; rg < 4; ++rg) {
        tl[(wid * 32 + l15) * 17 + l4 * 4 + rg]      = acc0[rg];
        tl[(wid * 32 + 16 + l15) * 17 + l4 * 4 + rg] = acc1[rg];
    }
    __syncthreads();
    #pragma unroll
    for (int q = 0; q < 8; ++q) {
        int idx = q * 64 + lane;
        int t = idx >> 4, il = idx & 15;
        int gi = ib * IB + wid * 16 + il;
        float val = tl[(wid * 32 + t) * 17 + il];
        part[((size_t)jb * TT + t) * NN + gi] = val;
        float cq = r[(size_t)t * NN + gi] * val;
        #pragma unroll
        for (int o = 8; o; o >>= 1) cq += __shfl_down(cq, o);
        if (il == 0) redb[wid][t] = cq;
    }
    __syncthreads();
    if (tid < 32) {
        float s = 0.f;
        #pragma unroll
        for (int u = 0; u < 4; ++u) s += redb[u][tid];
        rKvp[tid * 512 + bid] = s;
    }
}

// ---------------------------------------------------------------- Chronopoulos-Gear update (float2 per thread)
// Scalars by wave 0 (parallel reduce of 512 rKv partials + 4 rr partials), LDS-broadcast.
// ax += alpha*s. last: out[i][t] = ax_new - x_new  (y_pred = K@x = A@x - x).
__global__ __launch_bounds__(512) void cupd(const float* __restrict__ part, float* __restrict__ r,
                                            float* __restrict__ p, float* __restrict__ s_,
                                            float* __restrict__ x, float* __restrict__ ax,
                                            _Float16* __restrict__ vh,
                                            _Float16* __restrict__ vl,
                                            const float* __restrict__ rrp_in,
                                            float* __restrict__ rrp_out,
                                            const float* __restrict__ rKvp,
                                            const float* __restrict__ scal_in,
                                            float* __restrict__ scal_out,
                                            float* __restrict__ out,
                                            int first, int last) {
    const int t = blockIdx.x, c = blockIdx.y, tid = threadIdx.x;
    const int wid = tid >> 6, lane = tid & 63;
    __shared__ float sc2[2];
    __shared__ float red[8];
    if (wid == 0) {
        float rw_ = 0.f;
        #pragma unroll
        for (int u = 0; u < 8; ++u) rw_ += rKvp[t * 512 + u * 64 + lane];
        float rr_ = (lane < 4) ? rrp_in[t * 4 + lane] : 0.f;
        #pragma unroll
        for (int o = 32; o; o >>= 1) { rw_ += __shfl_down(rw_, o); rr_ += __shfl_down(rr_, o); }
        if (lane == 0) {
            float rr = rr_;
            float rw = rw_ + rr;                   // r.w = r.Kv + r.r  (A = K+I)
            float alpha, beta;
            if (first) { beta = 0.f; alpha = rr / rw; }
            else {
                float ap = scal_in[t], rrprev = scal_in[TT + t];
                beta = rr / rrprev;
                alpha = rr / (rw - (beta / ap) * rr);
            }
            sc2[0] = alpha; sc2[1] = beta;
            if (c == 0) { scal_out[t] = alpha; scal_out[TT + t] = rr; }
        }
    }
    __syncthreads();
    const float alpha = sc2[0], beta = sc2[1];
    int i = c * 1024 + tid * 2;
    size_t off = (size_t)t * NN + i;
    float2 sv = {0.f, 0.f};
    #pragma unroll
    for (int b = 0; b < JBP; ++b) {
        float2 pl = *(const float2*)&part[((size_t)b * TT + t) * NN + i];
        sv.x += pl.x; sv.y += pl.y;
    }
    float2 rv = *(const float2*)(r + off);
    float2 wv = { sv.x + rv.x, sv.y + rv.y };      // w = Kv + r
    float2 pv, sv2;
    if (first) { pv = rv; sv2 = wv; }
    else {
        float2 po = *(const float2*)(p + off);
        float2 so = *(const float2*)(s_ + off);
        pv  = { fmaf(beta, po.x, rv.x), fmaf(beta, po.y, rv.y) };
        sv2 = { fmaf(beta, so.x, wv.x), fmaf(beta, so.y, wv.y) };
    }
    *(float2*)(p + off) = pv;
    *(float2*)(s_ + off) = sv2;
    float2 xo  = first ? float2{0.f, 0.f} : *(const float2*)(x + off);
    float2 axo = first ? float2{0.f, 0.f} : *(const float2*)(ax + off);
    float2 xn  = { xo.x + alpha * pv.x,  xo.y + alpha * pv.y };
    float2 axn = { axo.x + alpha * sv2.x, axo.y + alpha * sv2.y };
    *(float2*)(x + off) = xn;
    *(float2*)(ax + off) = axn;
    float2 rn = { rv.x - alpha * sv2.x, rv.y - alpha * sv2.y };
    *(float2*)(r + off) = rn;
    if (last) {
        out[(size_t)i * TT + t]       = axn.x - xn.x;   // y_pred = A@x - x = K@x
        out[(size_t)(i + 1) * TT + t] = axn.y - xn.y;
    } else {
        _Float16 h0 = (_Float16)rn.x, h1 = (_Float16)rn.y;
        f16x2 hv = { h0, h1 };
        f16x2 lv = { (_Float16)(rn.x - (float)h0), (_Float16)(rn.y - (float)h1) };
        *(f16x2*)(vh + off) = hv;
        *(f16x2*)(vl + off) = lv;
    }
    float v = rn.x * rn.x + rn.y * rn.y;
    #pragma unroll
    for (int o = 32; o; o >>= 1) v += __shfl_down(v, o);
    if (lane == 0) red[wid] = v;
    __syncthreads();
    if (tid == 0) {
        float tot = 0.f;
        #pragma unroll
        for (int u = 0; u < 8; ++u) tot += red[u];
        rrp_out[t * 4 + c] = tot;
    }
}

extern "C" void kernel_launch(void* const* d_in, const int* in_sizes, int n_in,
                              void* d_out, int out_size, void* d_ws, size_t ws_size,
                              hipStream_t stream) {
    const float* X = (const float*)d_in[0];   // [N, D]
    const float* y = (const float*)d_in[1];   // [N, T]
    float* out = (float*)d_out;               // [N, T]

    unsigned char* wsb = (unsigned char*)d_ws;
    _Float16* Kh = (_Float16*)wsb;  wsb += (size_t)NN * NN * 2;          // 32 MB
    float* part  = (float*)wsb;     wsb += (size_t)JBP * TT * NN * 4;    // 4 MB
    float* r     = (float*)wsb;     wsb += (size_t)TT * NN * 4;
    float* p     = (float*)wsb;     wsb += (size_t)TT * NN * 4;
    float* s_    = (float*)wsb;     wsb += (size_t)TT * NN * 4;
    float* x     = (float*)wsb;     wsb += (size_t)TT * NN * 4;
    float* ax    = (float*)wsb;     wsb += (size_t)TT * NN * 4;
    _Float16* vh = (_Float16*)wsb;  wsb += (size_t)TT * NN * 2;
    _Float16* vl = (_Float16*)wsb;  wsb += (size_t)TT * NN * 2;
    _Float16* Xh = (_Float16*)wsb;  wsb += (size_t)NN * DD * 2;          // 2 MB
    float* x2v   = (float*)wsb;     wsb += (size_t)NN * 4;
    float* rrp   = (float*)wsb;     wsb += 256 * 4;                      // 2 slots x 128
    float* rKvp  = (float*)wsb;     wsb += (size_t)TT * 512 * 4;         // 64 KB
    float* scal  = (float*)wsb;     wsb += 128 * 4;                      // 2 slots x 64

    setup<<<1152, 256, 0, stream>>>(X, x2v, Xh, y, r, vh, vl, rrp);
    k_build<<<dim3(NN / 256, NN / 256), 512, 0, stream>>>(Xh, x2v, Kh);

    for (int j = 0; j < ITERS; ++j) {
        matvec_part<<<dim3(64, JBP), 256, 0, stream>>>(Kh, vh, vl, r, part, rKvp);
        cupd<<<dim3(TT, 4), 512, 0, stream>>>(part, r, p, s_, x, ax, vh, vl,
                                              rrp + (j & 1) * 128, rrp + ((j + 1) & 1) * 128,
                                              rKvp,
                                              scal + (j & 1) * 64, scal + ((j + 1) & 1) * 64,
                                              out,
                                              j == 0 ? 1 : 0, j == ITERS - 1 ? 1 : 0);
    }
}

// Round 14
// 180.844 us; speedup vs baseline: 10.0328x; 1.0387x over previous
//
#include <hip/hip_runtime.h>
#include <math.h>

#define NN 4096
#define DD 256
#define TT 32
#define GAMMA (1.0f/256.0f)
#define ITERS 10
#define LO_DROP 5        // iterations >= this use f16-only v (inexact-Krylov relaxation)
#define JBP 8            // j-chunks in matvec
#define JCH 512          // j per matvec block
#define IB  64           // i-rows per matvec block (4 waves)
#define BROW (JCH + 8)   // padded LDS row (f16 elems): 1040 B stride
#define KC  64           // k-chunk in k_build
#define KBP 72           // f16 elems per LDS row in k_build staging (64 + 8 pad)

typedef __attribute__((ext_vector_type(8))) _Float16 f16x8;
typedef __attribute__((ext_vector_type(4))) _Float16 f16x4;
typedef __attribute__((ext_vector_type(2))) _Float16 f16x2;
typedef __attribute__((ext_vector_type(4))) float f32x4;

// ---------------------------------------------------------------- setup: x2 + f16 X; CG init
// blocks [0,1024): x2conv (4 rows each). blocks [1024,1152): cg_init (one (t,c) each, c in 0..3).
__global__ __launch_bounds__(256) void setup(const float* __restrict__ X,
                                             float* __restrict__ x2,
                                             _Float16* __restrict__ Xh,
                                             const float* __restrict__ y,
                                             float* __restrict__ r,
                                             _Float16* __restrict__ vh,
                                             _Float16* __restrict__ vl,
                                             float* __restrict__ rrp) {
    const int b = blockIdx.x, tid = threadIdx.x;
    const int wid = tid >> 6, lane = tid & 63;
    if (b < 1024) {
        int row = b * 4 + wid;
        const float* xr = X + (size_t)row * DD;
        float4 v = *(const float4*)(xr + lane * 4);
        float s = v.x * v.x + v.y * v.y + v.z * v.z + v.w * v.w;
        #pragma unroll
        for (int o = 32; o; o >>= 1) s += __shfl_down(s, o);
        if (lane == 0) x2[row] = s;
        f16x4 h;
        h[0] = (_Float16)v.x; h[1] = (_Float16)v.y; h[2] = (_Float16)v.z; h[3] = (_Float16)v.w;
        *(f16x4*)(Xh + (size_t)row * DD + lane * 4) = h;
    } else {
        int bb = b - 1024;                    // 0..127
        int t = bb >> 2, c = bb & 3;          // 4 rr-partials per t (matches cupd grid.y = 4)
        float s = 0.f;
        #pragma unroll
        for (int pass = 0; pass < 4; ++pass) {
            int i = c * 1024 + pass * 256 + tid;
            float v = y[(size_t)i * TT + t];
            size_t off = (size_t)t * NN + i;
            r[off] = v;
            _Float16 h = (_Float16)v;
            vh[off] = h; vl[off] = (_Float16)(v - (float)h);
            s += v * v;
        }
        #pragma unroll
        for (int o = 32; o; o >>= 1) s += __shfl_down(s, o);
        __shared__ float red[4];
        if (lane == 0) red[wid] = s;
        __syncthreads();
        if (tid == 0) rrp[t * 4 + c] = red[0] + red[1] + red[2] + red[3];
    }
}

// ---------------------------------------------------------------- K = exp(-g*d2), f16 out
// 256(i) x 256(j) tile, 8 waves (2x4), wave tile 128x64. KC=64 staging.
__global__ __launch_bounds__(512) void k_build(const _Float16* __restrict__ Xh,
                                               const float* __restrict__ x2,
                                               _Float16* __restrict__ Kh) {
    __shared__ _Float16 As[256 * KBP];   // 36864 B
    __shared__ _Float16 Bs[256 * KBP];   // 36864 B
    const int i0 = blockIdx.x * 256, j0 = blockIdx.y * 256;
    const int tid = threadIdx.x;
    const int wid = tid >> 6, lane = tid & 63;
    const int wr = wid >> 2, wc = wid & 3;         // 2 x 4 waves, 128 x 64 each
    const int l15 = lane & 15, l4 = lane >> 4;
    f32x4 acc[8][4] = {};
    for (int kc = 0; kc < DD; kc += KC) {
        __syncthreads();
        #pragma unroll
        for (int s = 0; s < 4; ++s) {             // A: 256 rows x 8 chunks of 8
            int idx = s * 512 + tid;
            int row = idx >> 3, c = idx & 7;
            *(uint4*)(As + row * KBP + c * 8) =
                *(const uint4*)(Xh + (size_t)(i0 + row) * DD + kc + c * 8);
        }
        #pragma unroll
        for (int s = 0; s < 4; ++s) {             // B: 256 rows x 8 chunks of 8
            int idx = s * 512 + tid;
            int row = idx >> 3, c = idx & 7;
            *(uint4*)(Bs + row * KBP + c * 8) =
                *(const uint4*)(Xh + (size_t)(j0 + row) * DD + kc + c * 8);
        }
        __syncthreads();
        #pragma unroll
        for (int kk = 0; kk < 2; ++kk) {
            f16x8 af[8], bfr[4];
            #pragma unroll
            for (int m = 0; m < 8; ++m)
                af[m] = *(const f16x8*)(As + (wr * 128 + m * 16 + l15) * KBP + kk * 32 + l4 * 8);
            #pragma unroll
            for (int n = 0; n < 4; ++n)
                bfr[n] = *(const f16x8*)(Bs + (wc * 64 + n * 16 + l15) * KBP + kk * 32 + l4 * 8);
            #pragma unroll
            for (int m = 0; m < 8; ++m)
                #pragma unroll
                for (int n = 0; n < 4; ++n)
                    acc[m][n] = __builtin_amdgcn_mfma_f32_16x16x32_f16(af[m], bfr[n], acc[m][n], 0, 0, 0);
        }
    }
    #pragma unroll
    for (int m = 0; m < 8; ++m) {
        #pragma unroll
        for (int rg = 0; rg < 4; ++rg) {
            int i = i0 + wr * 128 + m * 16 + l4 * 4 + rg;
            float x2i = x2[i];
            #pragma unroll
            for (int n = 0; n < 4; ++n) {
                int j = j0 + wc * 64 + n * 16 + l15;
                float d2 = fmaxf(x2i + x2[j] - 2.f * acc[m][n][rg], 0.f);
                Kh[(size_t)i * NN + j] = (_Float16)__expf(-GAMMA * d2);
            }
        }
    }
}

// ---------------------------------------------------------------- matvec: part[jb][t][i] = sum_{j in jb} K[i][j]*v[t][j]
// Block = 64 i-rows (4 waves x 16) x 512 j; grid (64,8). USE_LO=0 halves LDS (4 blocks/CU) + MFMAs.
// Also emits rKvp[t][bid] = sum_{i in blk} r[t][i] * (Kv)[t][i]
template<int USE_LO>
__global__ __launch_bounds__(256) void matvec_part(const _Float16* __restrict__ Kh,
                                                   const _Float16* __restrict__ vh,
                                                   const _Float16* __restrict__ vl,
                                                   const float* __restrict__ r,
                                                   float* __restrict__ part,
                                                   float* __restrict__ rKvp) {
    __shared__ __align__(16) _Float16 Bbuf[(1 + USE_LO) * 32 * BROW];   // 33280 or 66560 B
    __shared__ float redb[4][33];
    _Float16* Bh = Bbuf;
    _Float16* Bl = Bbuf + (USE_LO ? 32 * BROW : 0);
    const int ib = blockIdx.x;                    // 64
    const int jb = blockIdx.y;                    // 8
    const int bid = jb * 64 + ib;                 // 0..511
    const int tid = threadIdx.x;
    const int wid = tid >> 6, lane = tid & 63;
    const int l15 = lane & 15, l4 = lane >> 4;
    // stage v: 32 t-rows x 512 j
    #pragma unroll
    for (int s = 0; s < 8; ++s) {
        int c = s * 256 + tid;                    // 2048 chunks of 8 f16
        int row = c >> 6, col8 = c & 63;
        *(uint4*)(Bh + row * BROW + col8 * 8) =
            *(const uint4*)(vh + (size_t)row * NN + jb * JCH + col8 * 8);
        if (USE_LO)
            *(uint4*)(Bl + row * BROW + col8 * 8) =
                *(const uint4*)(vl + (size_t)row * NN + jb * JCH + col8 * 8);
    }
    __syncthreads();
    const _Float16* Ap  = Kh + (size_t)(ib * IB + wid * 16 + l15) * NN + jb * JCH + l4 * 8;
    const _Float16* bhp = Bh + l15 * BROW + l4 * 8;
    const _Float16* blp = Bl + l15 * BROW + l4 * 8;
    f32x4 acc0 = {}, acc1 = {};
    #pragma unroll 4
    for (int jc = 0; jc < JCH; jc += 32) {
        f16x8 a   = *(const f16x8*)(Ap + jc);
        f16x8 bh0 = *(const f16x8*)(bhp + jc);
        f16x8 bh1 = *(const f16x8*)(bhp + 16 * BROW + jc);
        acc0 = __builtin_amdgcn_mfma_f32_16x16x32_f16(a, bh0, acc0, 0, 0, 0);
        acc1 = __builtin_amdgcn_mfma_f32_16x16x32_f16(a, bh1, acc1, 0, 0, 0);
        if (USE_LO) {
            f16x8 bl0 = *(const f16x8*)(blp + jc);
            f16x8 bl1 = *(const f16x8*)(blp + 16 * BROW + jc);
            acc0 = __builtin_amdgcn_mfma_f32_16x16x32_f16(a, bl0, acc0, 0, 0, 0);
            acc1 = __builtin_amdgcn_mfma_f32_16x16x32_f16(a, bl1, acc1, 0, 0, 0);
        }
    }
    __syncthreads();                               // done reading Bh/Bl -> reuse as tl
    float* tl = (float*)Bbuf;                      // [4][32][17] floats = 8704 B
    #pragma unroll
    for (int rg = 0; rg < 4; ++rg) {
        tl[(wid * 32 + l15) * 17 + l4 * 4 + rg]      = acc0[rg];
        tl[(wid * 32 + 16 + l15) * 17 + l4 * 4 + rg] = acc1[rg];
    }
    __syncthreads();
    #pragma unroll
    for (int q = 0; q < 8; ++q) {
        int idx = q * 64 + lane;
        int t = idx >> 4, il = idx & 15;
        int gi = ib * IB + wid * 16 + il;
        float val = tl[(wid * 32 + t) * 17 + il];
        part[((size_t)jb * TT + t) * NN + gi] = val;
        float cq = r[(size_t)t * NN + gi] * val;
        #pragma unroll
        for (int o = 8; o; o >>= 1) cq += __shfl_down(cq, o);
        if (il == 0) redb[wid][t] = cq;
    }
    __syncthreads();
    if (tid < 32) {
        float s = 0.f;
        #pragma unroll
        for (int u = 0; u < 4; ++u) s += redb[u][tid];
        rKvp[tid * 512 + bid] = s;
    }
}

// ---------------------------------------------------------------- Chronopoulos-Gear update (float2 per thread)
// Tracks d = A@x - x = sum_j alpha_j (s_j - p_j); last iter: out = d (y_pred = K@x).
__global__ __launch_bounds__(512) void cupd(const float* __restrict__ part, float* __restrict__ r,
                                            float* __restrict__ p, float* __restrict__ s_,
                                            float* __restrict__ d,
                                            _Float16* __restrict__ vh,
                                            _Float16* __restrict__ vl,
                                            const float* __restrict__ rrp_in,
                                            float* __restrict__ rrp_out,
                                            const float* __restrict__ rKvp,
                                            const float* __restrict__ scal_in,
                                            float* __restrict__ scal_out,
                                            float* __restrict__ out,
                                            int first, int last, int write_lo) {
    const int t = blockIdx.x, c = blockIdx.y, tid = threadIdx.x;
    const int wid = tid >> 6, lane = tid & 63;
    __shared__ float sc2[2];
    __shared__ float red[8];
    if (wid == 0) {
        float rw_ = 0.f;
        #pragma unroll
        for (int u = 0; u < 8; ++u) rw_ += rKvp[t * 512 + u * 64 + lane];
        float rr_ = (lane < 4) ? rrp_in[t * 4 + lane] : 0.f;
        #pragma unroll
        for (int o = 32; o; o >>= 1) { rw_ += __shfl_down(rw_, o); rr_ += __shfl_down(rr_, o); }
        if (lane == 0) {
            float rr = rr_;
            float rw = rw_ + rr;                   // r.w = r.Kv + r.r  (A = K+I)
            float alpha, beta;
            if (first) { beta = 0.f; alpha = rr / rw; }
            else {
                float ap = scal_in[t], rrprev = scal_in[TT + t];
                beta = rr / rrprev;
                alpha = rr / (rw - (beta / ap) * rr);
            }
            sc2[0] = alpha; sc2[1] = beta;
            if (c == 0) { scal_out[t] = alpha; scal_out[TT + t] = rr; }
        }
    }
    __syncthreads();
    const float alpha = sc2[0], beta = sc2[1];
    int i = c * 1024 + tid * 2;
    size_t off = (size_t)t * NN + i;
    float2 sv = {0.f, 0.f};
    #pragma unroll
    for (int b = 0; b < JBP; ++b) {
        float2 pl = *(const float2*)&part[((size_t)b * TT + t) * NN + i];
        sv.x += pl.x; sv.y += pl.y;
    }
    float2 rv = *(const float2*)(r + off);
    float2 wv = { sv.x + rv.x, sv.y + rv.y };      // w = Kv + r
    float2 pv, sv2;
    if (first) { pv = rv; sv2 = wv; }
    else {
        float2 po = *(const float2*)(p + off);
        float2 so = *(const float2*)(s_ + off);
        pv  = { fmaf(beta, po.x, rv.x), fmaf(beta, po.y, rv.y) };
        sv2 = { fmaf(beta, so.x, wv.x), fmaf(beta, so.y, wv.y) };
    }
    *(float2*)(p + off) = pv;
    *(float2*)(s_ + off) = sv2;
    float2 dn;
    if (first) {
        dn = { alpha * (sv2.x - pv.x), alpha * (sv2.y - pv.y) };
    } else {
        float2 dv = *(const float2*)(d + off);
        dn = { fmaf(alpha, sv2.x - pv.x, dv.x), fmaf(alpha, sv2.y - pv.y, dv.y) };
    }
    *(float2*)(d + off) = dn;
    float2 rn = { rv.x - alpha * sv2.x, rv.y - alpha * sv2.y };
    *(float2*)(r + off) = rn;
    if (last) {
        out[(size_t)i * TT + t]       = dn.x;      // y_pred = A@x - x = K@x
        out[(size_t)(i + 1) * TT + t] = dn.y;
    } else {
        _Float16 h0 = (_Float16)rn.x, h1 = (_Float16)rn.y;
        f16x2 hv = { h0, h1 };
        *(f16x2*)(vh + off) = hv;
        if (write_lo) {
            f16x2 lv = { (_Float16)(rn.x - (float)h0), (_Float16)(rn.y - (float)h1) };
            *(f16x2*)(vl + off) = lv;
        }
    }
    float v = rn.x * rn.x + rn.y * rn.y;
    #pragma unroll
    for (int o = 32; o; o >>= 1) v += __shfl_down(v, o);
    if (lane == 0) red[wid] = v;
    __syncthreads();
    if (tid == 0) {
        float tot = 0.f;
        #pragma unroll
        for (int u = 0; u < 8; ++u) tot += red[u];
        rrp_out[t * 4 + c] = tot;
    }
}

extern "C" void kernel_launch(void* const* d_in, const int* in_sizes, int n_in,
                              void* d_out, int out_size, void* d_ws, size_t ws_size,
                              hipStream_t stream) {
    const float* X = (const float*)d_in[0];   // [N, D]
    const float* y = (const float*)d_in[1];   // [N, T]
    float* out = (float*)d_out;               // [N, T]

    unsigned char* wsb = (unsigned char*)d_ws;
    _Float16* Kh = (_Float16*)wsb;  wsb += (size_t)NN * NN * 2;          // 32 MB
    float* part  = (float*)wsb;     wsb += (size_t)JBP * TT * NN * 4;    // 4 MB
    float* r     = (float*)wsb;     wsb += (size_t)TT * NN * 4;
    float* p     = (float*)wsb;     wsb += (size_t)TT * NN * 4;
    float* s_    = (float*)wsb;     wsb += (size_t)TT * NN * 4;
    float* d     = (float*)wsb;     wsb += (size_t)TT * NN * 4;
    _Float16* vh = (_Float16*)wsb;  wsb += (size_t)TT * NN * 2;
    _Float16* vl = (_Float16*)wsb;  wsb += (size_t)TT * NN * 2;
    _Float16* Xh = (_Float16*)wsb;  wsb += (size_t)NN * DD * 2;          // 2 MB
    float* x2v   = (float*)wsb;     wsb += (size_t)NN * 4;
    float* rrp   = (float*)wsb;     wsb += 256 * 4;                      // 2 slots x 128
    float* rKvp  = (float*)wsb;     wsb += (size_t)TT * 512 * 4;         // 64 KB
    float* scal  = (float*)wsb;     wsb += 128 * 4;                      // 2 slots x 64

    setup<<<1152, 256, 0, stream>>>(X, x2v, Xh, y, r, vh, vl, rrp);
    k_build<<<dim3(NN / 256, NN / 256), 512, 0, stream>>>(Xh, x2v, Kh);

    for (int j = 0; j < ITERS; ++j) {
        if (j < LO_DROP)
            matvec_part<1><<<dim3(64, JBP), 256, 0, stream>>>(Kh, vh, vl, r, part, rKvp);
        else
            matvec_part<0><<<dim3(64, JBP), 256, 0, stream>>>(Kh, vh, vl, r, part, rKvp);
        cupd<<<dim3(TT, 4), 512, 0, stream>>>(part, r, p, s_, d, vh, vl,
                                              rrp + (j & 1) * 128, rrp + ((j + 1) & 1) * 128,
                                              rKvp,
                                              scal + (j & 1) * 64, scal + ((j + 1) & 1) * 64,
                                              out,
                                              j == 0 ? 1 : 0, j == ITERS - 1 ? 1 : 0,
                                              (j + 1 < LO_DROP) ? 1 : 0);
    }
}